// Round 2
// baseline (383.561 us; speedup 1.0000x reference)
//
#include <hip/hip_runtime.h>
#include <hip/hip_bf16.h>
#include <math.h>

// Problem constants
#define B_   2
#define S_   2048
#define DM_  1024
#define H_   16
#define HD_  64
#define MEM_ 1000
#define KTOT 10
#define NROW (B_ * S_)          // 4096
#define NEG9 (-1e9f)
#define LDK  72                 // bf16 row stride in attention LDS tiles

// R10 work decomposition: items with qt>=20 split into 2 KV-halves.
#define NSPLITU 768             // 12 qt-groups (31..20) x 32 items x 2 parts
#define NSPLITI 384             // split items (need merge counters)
#define NUNITS  1408            // 768 split units + 20 qt-groups x 32 unsplit
#define PSLOT   4224            // floats per partial slot: 64x64 O + 64 m + 64 l
#define SC_     0.18033688f     // 0.125 * log2(e)  (QK scale, log2 domain)
#define TH_     170.238f        // 118 * log2(e)    (exact-underflow cutoff)

typedef __attribute__((ext_vector_type(8))) short short8;
typedef __attribute__((ext_vector_type(4))) float f32x4;

// async global->LDS, 16B per lane, dest = wave-uniform base + lane*16
__device__ __forceinline__ void gll16(const __hip_bfloat16* g, __hip_bfloat16* l) {
    __builtin_amdgcn_global_load_lds(
        (const __attribute__((address_space(1))) void*)g,
        (__attribute__((address_space(3))) void*)l, 16, 0, 0);
}

// ---------------------------------------------------------------------------
// prep: fused prologue (independent parts, branch on block range).
//   blocks [0,2048):    inputs fp32 -> bf16 Ax
//   blocks [2048,3072): weights fp32 -> transposed bf16 Wt[g*1024+n][k]
//   blocks [3072,3104): last-row K in fp32 (retrieval stays exact)
//   block 0 thread 0:   zero the attention work-steal counter
//   block 1:            zero the 384 split-merge counters
// ---------------------------------------------------------------------------
__global__ __launch_bounds__(256) void prep(const float* __restrict__ inputs,
                                            const float* __restrict__ Wq,
                                            const float* __restrict__ Wk,
                                            const float* __restrict__ Wv,
                                            const float* __restrict__ Wo,
                                            __hip_bfloat16* __restrict__ Ax,
                                            __hip_bfloat16* __restrict__ Wt,
                                            float* __restrict__ lk,
                                            int* __restrict__ ctr,
                                            int* __restrict__ done) {
    const int bx = blockIdx.x, tid = threadIdx.x;
    if (bx == 0 && tid == 0) *ctr = 0;
    if (bx == 1)
        for (int i = tid; i < NSPLITI; i += 256) done[i] = 0;

    if (bx < 2048) {
        const size_t i = ((size_t)bx * 256 + tid) * 8;
        float4 a = *(const float4*)&inputs[i];
        float4 b = *(const float4*)&inputs[i + 4];
        alignas(16) __hip_bfloat16 t[8];
        t[0] = __float2bfloat16(a.x); t[1] = __float2bfloat16(a.y);
        t[2] = __float2bfloat16(a.z); t[3] = __float2bfloat16(a.w);
        t[4] = __float2bfloat16(b.x); t[5] = __float2bfloat16(b.y);
        t[6] = __float2bfloat16(b.z); t[7] = __float2bfloat16(b.w);
        *(short8*)&Ax[i] = *(short8*)t;
        return;
    }
    if (bx < 3072) {
        const int idx = bx - 2048;
        const int g = idx >> 8, rem = idx & 255;
        const float* W = (g == 0) ? Wq : (g == 1) ? Wk : (g == 2) ? Wv : Wo;
        const int n0 = (rem & 15) * 64, k0 = (rem >> 4) * 64;
        __shared__ float T[64][65];
        {
            const int r = tid >> 4, c4 = (tid & 15) * 4;
#pragma unroll
            for (int p = 0; p < 4; ++p) {
                float4 v = *(const float4*)&W[(size_t)(k0 + r + p * 16) * 1024 + n0 + c4];
                T[r + p * 16][c4 + 0] = v.x; T[r + p * 16][c4 + 1] = v.y;
                T[r + p * 16][c4 + 2] = v.z; T[r + p * 16][c4 + 3] = v.w;
            }
        }
        __syncthreads();
        {
            const int n = tid >> 3, off = (tid & 7) * 8;
#pragma unroll
            for (int p = 0; p < 2; ++p) {
                const int nn = n + p * 32;
                alignas(16) __hip_bfloat16 t[8];
#pragma unroll
                for (int j = 0; j < 8; ++j) t[j] = __float2bfloat16(T[off + j][nn]);
                *(short8*)&Wt[((size_t)(g * 1024 + n0 + nn)) * 1024 + k0 + off] = *(short8*)t;
            }
        }
        return;
    }
    {   // lastk: lk[b,:] = inputs[b, S-1, :] @ Wk (fp32)
        const int idx = bx - 3072;
        const int xblk = idx & 15, b = idx >> 4;
        const int cl = tid & 63;
        const int col = xblk * 64 + cl;
        const int kq = tid >> 6;
        __shared__ float xr[1024];
        __shared__ float part[4][64];
        for (int i = tid; i < 1024; i += 256)
            xr[i] = inputs[((size_t)(b * S_ + S_ - 1)) * 1024 + i];
        __syncthreads();
        float acc = 0.f;
#pragma unroll 4
        for (int k = kq * 256; k < kq * 256 + 256; ++k)
            acc += xr[k] * Wk[(size_t)k * 1024 + col];
        part[kq][cl] = acc;
        __syncthreads();
        if (tid < 64)
            lk[b * 1024 + xblk * 64 + tid] =
                part[0][tid] + part[1][tid] + part[2][tid] + part[3][tid];
    }
}

// ---------------------------------------------------------------------------
// bf16 MFMA GEMM, m97 structure: BK=32, unpadded [128][32] LDS tiles staged
// with global_load_lds dwordx4. 128x128 tile, 4 waves, 16 MFMA per k-iter.
// ---------------------------------------------------------------------------
__device__ __forceinline__ void store_out(__hip_bfloat16* p, float x) { *p = __float2bfloat16(x); }
__device__ __forceinline__ void store_out(float* p, float x) { *p = x; }

template <typename OutT>
__global__ __launch_bounds__(256) void gemm_mfma(const __hip_bfloat16* __restrict__ A,
                                                 const __hip_bfloat16* __restrict__ Bt,
                                                 OutT* __restrict__ C, int ldc) {
    __shared__ __hip_bfloat16 As[128 * 32];
    __shared__ __hip_bfloat16 Bs[128 * 32];
    const int tid = threadIdx.x;
    const int wave = tid >> 6, lane = tid & 63;
    const int quad = lane >> 4, lm = lane & 15;
    const int wr = wave >> 1, wc = wave & 1;
    const int m0 = blockIdx.y * 128, n0 = blockIdx.x * 128;

    const int r0 = tid >> 2, c0 = (tid & 3) * 8;
    const __hip_bfloat16* ga0 = &A[(size_t)(m0 + r0) * 1024 + c0];
    const __hip_bfloat16* ga1 = &A[(size_t)(m0 + 64 + r0) * 1024 + c0];
    const __hip_bfloat16* gb0 = &Bt[(size_t)(n0 + r0) * 1024 + c0];
    const __hip_bfloat16* gb1 = &Bt[(size_t)(n0 + 64 + r0) * 1024 + c0];
    __hip_bfloat16* la0 = &As[(wave * 64) * 8];
    __hip_bfloat16* la1 = &As[(256 + wave * 64) * 8];
    __hip_bfloat16* lb0 = &Bs[(wave * 64) * 8];
    __hip_bfloat16* lb1 = &Bs[(256 + wave * 64) * 8];

    f32x4 acc[4][4];
#pragma unroll
    for (int i = 0; i < 4; ++i)
#pragma unroll
        for (int j = 0; j < 4; ++j) acc[i][j] = (f32x4){0.f, 0.f, 0.f, 0.f};

    for (int k0 = 0; k0 < 1024; k0 += 32) {
        __syncthreads();
        gll16(ga0 + k0, la0);
        gll16(ga1 + k0, la1);
        gll16(gb0 + k0, lb0);
        gll16(gb1 + k0, lb1);
        __syncthreads();
        short8 af[4], bf4[4];
#pragma unroll
        for (int mt = 0; mt < 4; ++mt)
            af[mt] = *(const short8*)&As[(wr * 64 + mt * 16 + lm) * 32 + quad * 8];
#pragma unroll
        for (int nt = 0; nt < 4; ++nt)
            bf4[nt] = *(const short8*)&Bs[(wc * 64 + nt * 16 + lm) * 32 + quad * 8];
#pragma unroll
        for (int mt = 0; mt < 4; ++mt)
#pragma unroll
            for (int nt = 0; nt < 4; ++nt)
                acc[mt][nt] = __builtin_amdgcn_mfma_f32_16x16x32_bf16(
                    af[mt], bf4[nt], acc[mt][nt], 0, 0, 0);
    }
#pragma unroll
    for (int mt = 0; mt < 4; ++mt)
#pragma unroll
        for (int nt = 0; nt < 4; ++nt) {
            const int col = n0 + wc * 64 + nt * 16 + lm;
#pragma unroll
            for (int i = 0; i < 4; ++i) {
                const int row = m0 + wr * 64 + mt * 16 + quad * 4 + i;
                store_out(&C[(size_t)row * ldc + col], acc[mt][nt][i]);
            }
        }
}

// ---------------------------------------------------------------------------
// 64x128-tile variant for the out-projection GEMM (kept from R9: grid (8,64)
// = 512 blocks = 2 blocks/CU; this change was the R9 win).
// ---------------------------------------------------------------------------
template <typename OutT>
__global__ __launch_bounds__(256) void gemm_mfma64(const __hip_bfloat16* __restrict__ A,
                                                   const __hip_bfloat16* __restrict__ Bt,
                                                   OutT* __restrict__ C, int ldc) {
    __shared__ __hip_bfloat16 As[64 * 32];
    __shared__ __hip_bfloat16 Bs[128 * 32];
    const int tid = threadIdx.x;
    const int wave = tid >> 6, lane = tid & 63;
    const int quad = lane >> 4, lm = lane & 15;
    const int wr = wave >> 1, wc = wave & 1;    // wave tile: 32 rows x 64 cols
    const int m0 = blockIdx.y * 64, n0 = blockIdx.x * 128;

    const int r0 = tid >> 2, c0 = (tid & 3) * 8;
    const __hip_bfloat16* ga  = &A[(size_t)(m0 + r0) * 1024 + c0];
    const __hip_bfloat16* gb0 = &Bt[(size_t)(n0 + r0) * 1024 + c0];
    const __hip_bfloat16* gb1 = &Bt[(size_t)(n0 + 64 + r0) * 1024 + c0];
    __hip_bfloat16* la  = &As[(wave * 64) * 8];
    __hip_bfloat16* lb0 = &Bs[(wave * 64) * 8];
    __hip_bfloat16* lb1 = &Bs[(256 + wave * 64) * 8];

    f32x4 acc[2][4];
#pragma unroll
    for (int i = 0; i < 2; ++i)
#pragma unroll
        for (int j = 0; j < 4; ++j) acc[i][j] = (f32x4){0.f, 0.f, 0.f, 0.f};

    for (int k0 = 0; k0 < 1024; k0 += 32) {
        __syncthreads();
        gll16(ga + k0, la);
        gll16(gb0 + k0, lb0);
        gll16(gb1 + k0, lb1);
        __syncthreads();
        short8 af[2], bf4[4];
#pragma unroll
        for (int mt = 0; mt < 2; ++mt)
            af[mt] = *(const short8*)&As[(wr * 32 + mt * 16 + lm) * 32 + quad * 8];
#pragma unroll
        for (int nt = 0; nt < 4; ++nt)
            bf4[nt] = *(const short8*)&Bs[(wc * 64 + nt * 16 + lm) * 32 + quad * 8];
#pragma unroll
        for (int mt = 0; mt < 2; ++mt)
#pragma unroll
            for (int nt = 0; nt < 4; ++nt)
                acc[mt][nt] = __builtin_amdgcn_mfma_f32_16x16x32_bf16(
                    af[mt], bf4[nt], acc[mt][nt], 0, 0, 0);
    }
#pragma unroll
    for (int mt = 0; mt < 2; ++mt)
#pragma unroll
        for (int nt = 0; nt < 4; ++nt) {
            const int col = n0 + wc * 64 + nt * 16 + lm;
#pragma unroll
            for (int i = 0; i < 4; ++i) {
                const int row = m0 + wr * 32 + mt * 16 + quad * 4 + i;
                store_out(&C[(size_t)row * ldc + col], acc[mt][nt][i]);
            }
        }
}

// ---------------------------------------------------------------------------
// sims[b][m] = (qvec . e_m) / (|e_m| + 1e-8)  (1/|q| > 0 cannot change order).
// ---------------------------------------------------------------------------
__global__ __launch_bounds__(256) void sims_kernel(const float* __restrict__ lk,
                                                   const float* __restrict__ events,
                                                   float* __restrict__ sims) {
    const int b = blockIdx.y;
    const int tid = threadIdx.x;
    const int wave = tid >> 6, lane = tid & 63;
    __shared__ float qv[1024];
    for (int i = tid; i < 1024; i += 256)
        qv[i] = lk[b * 1024 + i];
    __syncthreads();

    const int m = blockIdx.x * 4 + wave;
    if (m >= MEM_) return;
    const float* ev = &events[(size_t)m * 1024];
    float dot = 0.f, nrm = 0.f;
    for (int d = lane; d < 1024; d += 64) {
        float e = ev[d];
        dot += qv[d] * e;
        nrm += e * e;
    }
    for (int off = 32; off; off >>= 1) {
        dot += __shfl_down(dot, off);
        nrm += __shfl_down(nrm, off);
    }
    if (lane == 0) sims[b * 1024 + m] = dot / (sqrtf(nrm) + 1e-8f);
}

// ---------------------------------------------------------------------------
// Top-10, single wave per batch: 16 values/lane in registers, shuffle-only
// argmax x10, smaller-index tie-break. No barriers, no LDS.
// ---------------------------------------------------------------------------
__global__ __launch_bounds__(64) void topk10_kernel(const float* __restrict__ sims,
                                                    int* __restrict__ topk) {
    const int b = blockIdx.x;
    const int lane = threadIdx.x;
    const int base = lane * 16;
    float v[16];
#pragma unroll
    for (int j = 0; j < 16; ++j) {
        const int m = base + j;
        v[j] = (m < MEM_) ? sims[b * 1024 + m] : -INFINITY;
    }
    for (int it = 0; it < KTOT; ++it) {
        float best = -INFINITY; int bi = 0x7fffffff;
#pragma unroll
        for (int j = 0; j < 16; ++j)
            if (v[j] > best) { best = v[j]; bi = base + j; }   // strict > keeps smallest idx
        for (int off = 32; off; off >>= 1) {
            const float ob = __shfl_xor(best, off);
            const int   oi = __shfl_xor(bi, off);
            if (ob > best || (ob == best && oi < bi)) { best = ob; bi = oi; }
        }
        if (lane == 0) topk[b * KTOT + it] = bi;
#pragma unroll
        for (int j = 0; j < 16; ++j)
            if (base + j == bi) v[j] = -INFINITY;
    }
}

// ---------------------------------------------------------------------------
// Flash attention, bf16 MFMA, persistent blocks + work stealing.
// R10 (post-mortem of R9: dbuf/1-barrier was NEUTRAL->negative; occupancy
// 20.7% vs 37.5% resident ceiling + 33-tile max item => latency/balance
// bound, not barrier bound):
//  * SINGLE-buffer LDS again (30.7 KB, R8-proven) -> 5 blocks/CU; grid 1280
//    = 20 waves/CU resident (was 12). LDS addrs loop-invariant again.
//  * KV-SPLIT: items with qt>=20 split into two halves (lower = mem+[0,mid),
//    upper = [mid,qt]); each runs independent online softmax (own m, l via
//    ones-column). 1408 units, max unit 21 tiles (was 33). Partial
//    (unnormalized O f32 + per-row m,l) -> slots in the DEAD Ax/Wq/Wk ws
//    region (gemm1 done before attn; Wo at +14.7MB untouched, partials end
//    at 13.0MB). Last finisher (threadfence + atomic counter, split-K
//    protocol) merges and writes out. Per-half frozen-max cutoff stays
//    exact (bound uses only the half's own running max).
//  * softmax in log2 domain (exp2f; 0.125*log2e folded into scale/slopes/
//    cutoff): one fewer v_mul per exp.
// Kept: ones-column l-accumulator, Q-in-regs, reg prefetch of next K/V tile,
// zero-once Vt init (stale finite x P==0 is exact).
// ---------------------------------------------------------------------------
__global__ __launch_bounds__(256) void attn_mfma(
        const __hip_bfloat16* __restrict__ qkv,
        const float* __restrict__ events,
        const int* __restrict__ topk,
        const float* __restrict__ amask,
        __hip_bfloat16* __restrict__ out,
        int* __restrict__ ctr,
        int* __restrict__ done,
        float* __restrict__ partb) {
    const int tid = threadIdx.x;
    const int wave = tid >> 6, lane = tid & 63;
    const int quad = lane >> 4, lm = lane & 15;

    const __hip_bfloat16* qf = qkv;
    const __hip_bfloat16* kf = qkv + 1024;
    const __hip_bfloat16* vf = qkv + 2048;

    __shared__ __hip_bfloat16 Ks[64 * LDK];
    __shared__ __hip_bfloat16 Vt[80 * LDK];   // [d][kcol]; rows 64..79 static (64=ones)
    __shared__ __hip_bfloat16 Ps[64 * LDK];
    __shared__ float colb[64];
    __shared__ float redb[4];
    __shared__ int sItem;
    __shared__ int sOld;

    const int va = tid & 31, vdc = tid >> 5;
    const int vtok0 = va * 2, vd0 = vdc * 8;

    // one-time init: finite fill of dynamic Vt rows (stale-x-0 = 0 needs
    // finite, not NaN), and the static ones/zero rows.
    for (int i = tid * 8; i < 64 * LDK; i += 256 * 8)
        *(int4*)&Vt[i] = make_int4(0, 0, 0, 0);
    for (int i = tid; i < 16 * LDK; i += 256) {
        const int r = i / LDK;
        Vt[64 * LDK + i] = __float2bfloat16(r == 0 ? 1.0f : 0.0f);
    }

    for (;;) {
        __syncthreads();    // prev unit's LDS readers done; also covers Vt init
        if (tid == 0) sItem = atomicAdd(ctr, 1);
        __syncthreads();
        const int n = sItem;
        if (n >= NUNITS) break;

        int qt, inner, kstart, kend, nparts, slot = 0, sidx = 0;
        bool haveMem;
        if (n < NSPLITU) {
            qt = 31 - (n >> 6);
            const int rem = n & 63;
            const int prt = rem >> 5;       // 0 = lower (with mem), 1 = upper
            inner = rem & 31;
            const int mid = (qt + 1) >> 1;
            kstart = prt ? mid : 0;
            kend   = prt ? qt : (mid - 1);
            haveMem = (prt == 0);
            nparts = 2;
            sidx = (31 - qt) * 32 + inner;
            slot = sidx * 2 + prt;
        } else {
            const int n2 = n - NSPLITU;
            qt = 19 - (n2 >> 5);
            inner = n2 & 31;
            kstart = 0; kend = qt; haveMem = true; nparts = 1;
        }
        const int q0 = qt * 64;
        const int h = 15 - ((inner >> 1) & 15);
        const int b = inner & 1;
        const float slope2 = exp2f(-0.5f * (float)(h + 1)) * 1.44269504f;  // log2 dom

        short8 pk[2], pv0, pv1;
        float pam = 1.f;
        auto prefetchKV = [&](int kt) {
            const __hip_bfloat16* ks = &kf[((size_t)(b * S_ + kt * 64)) * 3072 + h * 64];
#pragma unroll
            for (int u = 0; u < 2; ++u) {
                int c = tid * 2 + u, row = c >> 3, off = (c & 7) * 8;
                pk[u] = *(const short8*)&ks[(size_t)row * 3072 + off];
            }
            const __hip_bfloat16* v0 =
                &vf[((size_t)(b * S_ + kt * 64 + vtok0)) * 3072 + h * 64 + vd0];
            pv0 = *(const short8*)v0;
            pv1 = *(const short8*)(v0 + 3072);
            if (tid < 64) pam = amask[b * S_ + kt * 64 + tid];
        };
        auto stageKV = [&](int kt) {
#pragma unroll
            for (int u = 0; u < 2; ++u) {
                int c = tid * 2 + u, row = c >> 3, off = (c & 7) * 8;
                *(short8*)&Ks[row * LDK + off] = pk[u];
            }
#pragma unroll
            for (int j = 0; j < 8; ++j) {
                short2 pr; pr.x = pv0[j]; pr.y = pv1[j];
                *(short2*)&Vt[(vd0 + j) * LDK + vtok0] = pr;
            }
            if (tid < 64)
                colb[tid] = fmaf(-slope2, (float)(kt * 64 + tid), (1.f - pam) * NEG9);
        };

        prefetchKV(kstart);     // earliest possible issue; consumed by stageKV(kstart)

        // ---- Q fragments straight into registers ----
        short8 qa[2];
        {
            const __hip_bfloat16* qsrc =
                &qf[((size_t)(b * S_ + q0 + wave * 16 + lm)) * 3072 + h * 64 + quad * 8];
            qa[0] = *(const short8*)qsrc;
            qa[1] = *(const short8*)(qsrc + 32);
        }
        // memory tile (K rows 0..9; Vt cols 0..9; stale rest is masked:
        // Ks via cc>=KTOT -> NEG9 before use, Vt via Ps == 0.0 exactly)
        if (haveMem && tid < 80) {
            const int tok = tid >> 3, d0 = (tid & 7) * 8;
            const int ev = topk[b * KTOT + tok];
            const float* es = &events[(size_t)ev * 1024 + h * 64 + d0];
#pragma unroll
            for (int j = 0; j < 8; ++j) {
                __hip_bfloat16 x = __float2bfloat16(es[j]);
                Ks[tok * LDK + d0 + j] = x;
                Vt[(d0 + j) * LDK + tok] = x;
            }
        }

        float m_[4], mshift[4];
        f32x4 Oa[5];        // Oa[4] = softmax denominator column
#pragma unroll
        for (int i = 0; i < 4; ++i) {
            m_[i] = -INFINITY;
            mshift[i] = -slope2 * (float)(q0 + wave * 16 + quad * 4 + i);
        }
#pragma unroll
        for (int nt = 0; nt < 5; ++nt) Oa[nt] = (f32x4){0.f, 0.f, 0.f, 0.f};

        auto qk = [&](f32x4* sa) {
#pragma unroll
            for (int nt = 0; nt < 4; ++nt) sa[nt] = (f32x4){0.f, 0.f, 0.f, 0.f};
#pragma unroll
            for (int ks2 = 0; ks2 < 2; ++ks2) {
#pragma unroll
                for (int nt = 0; nt < 4; ++nt) {
                    short8 bk = *(const short8*)&Ks[(nt * 16 + lm) * LDK + ks2 * 32 + quad * 8];
                    sa[nt] = __builtin_amdgcn_mfma_f32_16x16x32_bf16(qa[ks2], bk, sa[nt], 0, 0, 0);
                }
            }
        };
        auto pv = [&]() {
#pragma unroll
            for (int ks2 = 0; ks2 < 2; ++ks2) {
                short8 ap = *(const short8*)&Ps[(wave * 16 + lm) * LDK + ks2 * 32 + quad * 8];
#pragma unroll
                for (int nt = 0; nt < 5; ++nt) {   // nt=4: ones column -> l
                    short8 bv = *(const short8*)&Vt[(nt * 16 + lm) * LDK + ks2 * 32 + quad * 8];
                    Oa[nt] = __builtin_amdgcn_mfma_f32_16x16x32_bf16(ap, bv, Oa[nt], 0, 0, 0);
                }
            }
        };

        auto softmax_online = [&](const f32x4* sa, int kt, bool diag) {
            float cb[4];
            if (kt >= 0) {
#pragma unroll
                for (int nt = 0; nt < 4; ++nt) cb[nt] = colb[nt * 16 + lm];
            }
#pragma unroll
            for (int i = 0; i < 4; ++i) {
                const int lr = wave * 16 + quad * 4 + i;
                const int rg = q0 + lr;
                float s[4];
#pragma unroll
                for (int nt = 0; nt < 4; ++nt) {
                    const int cc = nt * 16 + lm;
                    if (kt < 0) {
                        s[nt] = (cc < KTOT) ? fmaf(sa[nt][i], SC_, mshift[i]) : NEG9;
                    } else {
                        float v = fmaf(sa[nt][i], SC_, cb[nt]);
                        s[nt] = (diag && kt * 64 + cc > rg) ? NEG9 : v;
                    }
                }
                float rmax = fmaxf(fmaxf(s[0], s[1]), fmaxf(s[2], s[3]));
#pragma unroll
                for (int off = 1; off < 16; off <<= 1)
                    rmax = fmaxf(rmax, __shfl_xor(rmax, off, 16));
                const float newm = fmaxf(m_[i], rmax);
                const float al = exp2f(m_[i] - newm);
                m_[i] = newm;
#pragma unroll
                for (int nt = 0; nt < 4; ++nt)
                    Ps[lr * LDK + nt * 16 + lm] = __float2bfloat16(exp2f(s[nt] - newm));
#pragma unroll
                for (int nt = 0; nt < 5; ++nt)     // includes l-column
                    Oa[nt][i] *= al;
            }
        };

        auto softmax_fast = [&](const f32x4* sa, int cbase, bool diag) {
            float cb[4];
#pragma unroll
            for (int nt = 0; nt < 4; ++nt) cb[nt] = colb[nt * 16 + lm];
#pragma unroll
            for (int i = 0; i < 4; ++i) {
                const int lr = wave * 16 + quad * 4 + i;
                const float cm = m_[i];
                float p[4];
#pragma unroll
                for (int nt = 0; nt < 4; ++nt)
                    p[nt] = exp2f(fmaf(sa[nt][i], SC_, cb[nt]) - cm);
                if (diag) {
                    const int rg = q0 + lr;
#pragma unroll
                    for (int nt = 0; nt < 4; ++nt)
                        if (cbase + nt * 16 + lm > rg) p[nt] = 0.f;
                }
#pragma unroll
                for (int nt = 0; nt < 4; ++nt)
                    Ps[lr * LDK + nt * 16 + lm] = __float2bfloat16(p[nt]);
            }
        };

        // ---- memory tile (online) ----
        if (haveMem) {
            __syncthreads();        // publish mem tile
            f32x4 sa[4];
            qk(sa);
            softmax_online(sa, -1, false);
            pv();
        }
        // ---- first regular tile kt = kstart (online) ----
        __syncthreads();            // mem readers done (or unit top for upper)
        stageKV(kstart);
        if (kstart < kend) prefetchKV(kstart + 1);
        __syncthreads();
        {
            f32x4 sa[4];
            qk(sa);
            softmax_online(sa, kstart, kstart == qt);
            pv();
        }

        // ---- freeze max; block-min(m) -> exact-underflow cutoff ----
        int kend2 = kstart;
        if (kend > kstart) {
            float mloc = fminf(fminf(m_[0], m_[1]), fminf(m_[2], m_[3]));
#pragma unroll
            for (int off = 1; off < 64; off <<= 1)
                mloc = fminf(mloc, __shfl_xor(mloc, off, 64));
            if (lane == 0) redb[wave] = mloc;
            __syncthreads();        // redb visible + first-tile readers done
            const float mmin = fminf(fminf(redb[0], redb[1]), fminf(redb[2], redb[3]));
            kend2 = min(kend, (int)((TH_ - mmin) / (64.f * slope2)));
        }
        for (int kt = kstart + 1; kt <= kend2; ++kt) {
            stageKV(kt);
            if (kt < kend2) prefetchKV(kt + 1);
            __syncthreads();        // publish tile kt
            f32x4 sa[4];
            qk(sa);
            softmax_fast(sa, kt * 64, kt == qt);
            pv();
            __syncthreads();        // readers done before next stage
        }

        // ---- epilogue ----
        if (nparts == 1) {
            // l lives in Oa[4] col 0 (lanes lm==0); broadcast
#pragma unroll
            for (int i = 0; i < 4; ++i) {
                const int lr = wave * 16 + quad * 4 + i;
                const float l = __shfl(Oa[4][i], (lane & 48));
                const float inv = 1.f / l;
                __hip_bfloat16* dst = &out[((size_t)(b * S_ + q0 + lr)) * 1024 + h * 64 + lm];
#pragma unroll
                for (int nt = 0; nt < 4; ++nt)
                    dst[nt * 16] = __float2bfloat16(Oa[nt][i] * inv);
            }
        } else {
            // split half: dump partial (unnormalized O + per-row m,l), then
            // last finisher merges (threadfence + counter, split-K protocol).
            float l_[4];
#pragma unroll
            for (int i = 0; i < 4; ++i) l_[i] = __shfl(Oa[4][i], (lane & 48));
            float* psl = partb + (size_t)slot * PSLOT;
#pragma unroll
            for (int i = 0; i < 4; ++i) {
                const int lr = wave * 16 + quad * 4 + i;
#pragma unroll
                for (int nt = 0; nt < 4; ++nt)
                    psl[lr * 64 + nt * 16 + lm] = Oa[nt][i];
                if (lm == 0) {
                    psl[4096 + lr] = m_[i];
                    psl[4160 + lr] = l_[i];
                }
            }
            __threadfence();
            if (tid == 0) sOld = atomicAdd(&done[sidx], 1);
            __syncthreads();
            if (sOld == 1) {
                __threadfence();    // acquire partner's writes
                const float* po = partb + (size_t)(slot ^ 1) * PSLOT;
#pragma unroll
                for (int i = 0; i < 4; ++i) {
                    const int lr = wave * 16 + quad * 4 + i;
                    const float m2 = po[4096 + lr], l2 = po[4160 + lr];
                    const float mm = fmaxf(m_[i], m2);
                    const float f1 = exp2f(m_[i] - mm), f2 = exp2f(m2 - mm);
                    const float inv = 1.f / (l_[i] * f1 + l2 * f2);
                    __hip_bfloat16* dst =
                        &out[((size_t)(b * S_ + q0 + lr)) * 1024 + h * 64 + lm];
#pragma unroll
                    for (int nt = 0; nt < 4; ++nt)
                        dst[nt * 16] = __float2bfloat16(
                            (Oa[nt][i] * f1 + po[lr * 64 + nt * 16 + lm] * f2) * inv);
                }
            }
        }
    }
}

// ---------------------------------------------------------------------------
extern "C" void kernel_launch(void* const* d_in, const int* in_sizes, int n_in,
                              void* d_out, int out_size, void* d_ws, size_t ws_size,
                              hipStream_t stream) {
    const float* inputs = (const float*)d_in[0];
    const float* amask  = (const float*)d_in[1];
    const float* Wq     = (const float*)d_in[2];
    const float* Wk     = (const float*)d_in[3];
    const float* Wv     = (const float*)d_in[4];
    const float* Wo     = (const float*)d_in[5];
    const float* events = (const float*)d_in[6];
    float* out = (float*)d_out;

    // ws: Ax 8MB | Wt 8MB | qkv 24MB | ao 8MB | lk | sims | topk | ctr | done
    // During attn, [Ax .. Ax+13.0MB) is dead (gemm1 done; Wo lives at
    // +14.7MB) and is reused for the 768 split-merge partial slots.
    __hip_bfloat16* Ax  = (__hip_bfloat16*)d_ws;
    __hip_bfloat16* Wt  = Ax + (size_t)NROW * 1024;
    __hip_bfloat16* qkv = Wt + (size_t)4096 * 1024;
    __hip_bfloat16* ao  = qkv + (size_t)NROW * 3072;
    float* lk   = (float*)(ao + (size_t)NROW * 1024);
    float* sims = lk + 2 * 1024;
    int* topk   = (int*)(sims + 2 * 1024);
    int* ctr    = topk + B_ * KTOT;
    int* done   = ctr + 1;
    float* partb = (float*)d_ws;    // aliases Ax/Wq/Wk region (dead during attn)

    dim3 blk(256);
    prep<<<3104, blk, 0, stream>>>(inputs, Wq, Wk, Wv, Wo, Ax, Wt, lk, ctr, done);
    sims_kernel<<<dim3(250, B_), blk, 0, stream>>>(lk, events, sims);
    topk10_kernel<<<B_, 64, 0, stream>>>(sims, topk);
    gemm_mfma<__hip_bfloat16><<<dim3(24, 32), blk, 0, stream>>>(Ax, Wt, qkv, 3072);
    attn_mfma<<<1280, blk, 0, stream>>>(qkv, events, topk, amask, ao, ctr, done, partb);
    gemm_mfma64<float><<<dim3(8, 64), blk, 0, stream>>>(
        ao, Wt + (size_t)3072 * 1024, out, 1024);
}

// Round 3
// 272.609 us; speedup vs baseline: 1.4070x; 1.4070x over previous
//
#include <hip/hip_runtime.h>
#include <hip/hip_bf16.h>
#include <math.h>

// Problem constants
#define B_   2
#define S_   2048
#define DM_  1024
#define H_   16
#define HD_  64
#define MEM_ 1000
#define KTOT 10
#define NROW (B_ * S_)          // 4096
#define NEG9 (-1e9f)
#define LDK  72                 // bf16 row stride in attention LDS tiles
#define NITEMS 1024             // attention work items: 32 qt x 16 h x 2 b
#define SC_  0.18033688f        // 0.125 * log2(e)  (QK scale, log2 domain)
#define TH_  170.238f           // 118 * log2(e)    (exact-underflow cutoff)

typedef __attribute__((ext_vector_type(8))) short short8;
typedef __attribute__((ext_vector_type(4))) short s16x4;
typedef __attribute__((ext_vector_type(4))) float f32x4;

__device__ __forceinline__ float __exp2(float x) { return __builtin_amdgcn_exp2f(x); }

// async global->LDS, 16B per lane, dest = wave-uniform base + lane*16
__device__ __forceinline__ void gll16(const __hip_bfloat16* g, __hip_bfloat16* l) {
    __builtin_amdgcn_global_load_lds(
        (const __attribute__((address_space(1))) void*)g,
        (__attribute__((address_space(3))) void*)l, 16, 0, 0);
}

// ---------------------------------------------------------------------------
// prep: fused prologue (independent parts, branch on block range).
// ---------------------------------------------------------------------------
__global__ __launch_bounds__(256) void prep(const float* __restrict__ inputs,
                                            const float* __restrict__ Wq,
                                            const float* __restrict__ Wk,
                                            const float* __restrict__ Wv,
                                            const float* __restrict__ Wo,
                                            __hip_bfloat16* __restrict__ Ax,
                                            __hip_bfloat16* __restrict__ Wt,
                                            float* __restrict__ lk,
                                            int* __restrict__ ctr) {
    const int bx = blockIdx.x, tid = threadIdx.x;
    if (bx == 0 && tid == 0) *ctr = 0;

    if (bx < 2048) {
        const size_t i = ((size_t)bx * 256 + tid) * 8;
        float4 a = *(const float4*)&inputs[i];
        float4 b = *(const float4*)&inputs[i + 4];
        alignas(16) __hip_bfloat16 t[8];
        t[0] = __float2bfloat16(a.x); t[1] = __float2bfloat16(a.y);
        t[2] = __float2bfloat16(a.z); t[3] = __float2bfloat16(a.w);
        t[4] = __float2bfloat16(b.x); t[5] = __float2bfloat16(b.y);
        t[6] = __float2bfloat16(b.z); t[7] = __float2bfloat16(b.w);
        *(short8*)&Ax[i] = *(short8*)t;
        return;
    }
    if (bx < 3072) {
        const int idx = bx - 2048;
        const int g = idx >> 8, rem = idx & 255;
        const float* W = (g == 0) ? Wq : (g == 1) ? Wk : (g == 2) ? Wv : Wo;
        const int n0 = (rem & 15) * 64, k0 = (rem >> 4) * 64;
        __shared__ float T[64][65];
        {
            const int r = tid >> 4, c4 = (tid & 15) * 4;
#pragma unroll
            for (int p = 0; p < 4; ++p) {
                float4 v = *(const float4*)&W[(size_t)(k0 + r + p * 16) * 1024 + n0 + c4];
                T[r + p * 16][c4 + 0] = v.x; T[r + p * 16][c4 + 1] = v.y;
                T[r + p * 16][c4 + 2] = v.z; T[r + p * 16][c4 + 3] = v.w;
            }
        }
        __syncthreads();
        {
            const int n = tid >> 3, off = (tid & 7) * 8;
#pragma unroll
            for (int p = 0; p < 2; ++p) {
                const int nn = n + p * 32;
                alignas(16) __hip_bfloat16 t[8];
#pragma unroll
                for (int j = 0; j < 8; ++j) t[j] = __float2bfloat16(T[off + j][nn]);
                *(short8*)&Wt[((size_t)(g * 1024 + n0 + nn)) * 1024 + k0 + off] = *(short8*)t;
            }
        }
        return;
    }
    {   // lastk: lk[b,:] = inputs[b, S-1, :] @ Wk (fp32)
        const int idx = bx - 3072;
        const int xblk = idx & 15, b = idx >> 4;
        const int cl = tid & 63;
        const int col = xblk * 64 + cl;
        const int kq = tid >> 6;
        __shared__ float xr[1024];
        __shared__ float part[4][64];
        for (int i = tid; i < 1024; i += 256)
            xr[i] = inputs[((size_t)(b * S_ + S_ - 1)) * 1024 + i];
        __syncthreads();
        float acc = 0.f;
#pragma unroll 4
        for (int k = kq * 256; k < kq * 256 + 256; ++k)
            acc += xr[k] * Wk[(size_t)k * 1024 + col];
        part[kq][cl] = acc;
        __syncthreads();
        if (tid < 64)
            lk[b * 1024 + xblk * 64 + tid] =
                part[0][tid] + part[1][tid] + part[2][tid] + part[3][tid];
    }
}

// ---------------------------------------------------------------------------
// bf16 MFMA GEMM, m97 structure (unchanged, proven).
// ---------------------------------------------------------------------------
__device__ __forceinline__ void store_out(__hip_bfloat16* p, float x) { *p = __float2bfloat16(x); }
__device__ __forceinline__ void store_out(float* p, float x) { *p = x; }

template <typename OutT>
__global__ __launch_bounds__(256) void gemm_mfma(const __hip_bfloat16* __restrict__ A,
                                                 const __hip_bfloat16* __restrict__ Bt,
                                                 OutT* __restrict__ C, int ldc) {
    __shared__ __hip_bfloat16 As[128 * 32];
    __shared__ __hip_bfloat16 Bs[128 * 32];
    const int tid = threadIdx.x;
    const int wave = tid >> 6, lane = tid & 63;
    const int quad = lane >> 4, lm = lane & 15;
    const int wr = wave >> 1, wc = wave & 1;
    const int m0 = blockIdx.y * 128, n0 = blockIdx.x * 128;

    const int r0 = tid >> 2, c0 = (tid & 3) * 8;
    const __hip_bfloat16* ga0 = &A[(size_t)(m0 + r0) * 1024 + c0];
    const __hip_bfloat16* ga1 = &A[(size_t)(m0 + 64 + r0) * 1024 + c0];
    const __hip_bfloat16* gb0 = &Bt[(size_t)(n0 + r0) * 1024 + c0];
    const __hip_bfloat16* gb1 = &Bt[(size_t)(n0 + 64 + r0) * 1024 + c0];
    __hip_bfloat16* la0 = &As[(wave * 64) * 8];
    __hip_bfloat16* la1 = &As[(256 + wave * 64) * 8];
    __hip_bfloat16* lb0 = &Bs[(wave * 64) * 8];
    __hip_bfloat16* lb1 = &Bs[(256 + wave * 64) * 8];

    f32x4 acc[4][4];
#pragma unroll
    for (int i = 0; i < 4; ++i)
#pragma unroll
        for (int j = 0; j < 4; ++j) acc[i][j] = (f32x4){0.f, 0.f, 0.f, 0.f};

    for (int k0 = 0; k0 < 1024; k0 += 32) {
        __syncthreads();
        gll16(ga0 + k0, la0);
        gll16(ga1 + k0, la1);
        gll16(gb0 + k0, lb0);
        gll16(gb1 + k0, lb1);
        __syncthreads();
        short8 af[4], bf4[4];
#pragma unroll
        for (int mt = 0; mt < 4; ++mt)
            af[mt] = *(const short8*)&As[(wr * 64 + mt * 16 + lm) * 32 + quad * 8];
#pragma unroll
        for (int nt = 0; nt < 4; ++nt)
            bf4[nt] = *(const short8*)&Bs[(wc * 64 + nt * 16 + lm) * 32 + quad * 8];
#pragma unroll
        for (int mt = 0; mt < 4; ++mt)
#pragma unroll
            for (int nt = 0; nt < 4; ++nt)
                acc[mt][nt] = __builtin_amdgcn_mfma_f32_16x16x32_bf16(
                    af[mt], bf4[nt], acc[mt][nt], 0, 0, 0);
    }
#pragma unroll
    for (int mt = 0; mt < 4; ++mt)
#pragma unroll
        for (int nt = 0; nt < 4; ++nt) {
            const int col = n0 + wc * 64 + nt * 16 + lm;
#pragma unroll
            for (int i = 0; i < 4; ++i) {
                const int row = m0 + wr * 64 + mt * 16 + quad * 4 + i;
                store_out(&C[(size_t)row * ldc + col], acc[mt][nt][i]);
            }
        }
}

// ---------------------------------------------------------------------------
// 64x128-tile variant for the out-projection GEMM (R9 win, kept).
// ---------------------------------------------------------------------------
template <typename OutT>
__global__ __launch_bounds__(256) void gemm_mfma64(const __hip_bfloat16* __restrict__ A,
                                                   const __hip_bfloat16* __restrict__ Bt,
                                                   OutT* __restrict__ C, int ldc) {
    __shared__ __hip_bfloat16 As[64 * 32];
    __shared__ __hip_bfloat16 Bs[128 * 32];
    const int tid = threadIdx.x;
    const int wave = tid >> 6, lane = tid & 63;
    const int quad = lane >> 4, lm = lane & 15;
    const int wr = wave >> 1, wc = wave & 1;
    const int m0 = blockIdx.y * 64, n0 = blockIdx.x * 128;

    const int r0 = tid >> 2, c0 = (tid & 3) * 8;
    const __hip_bfloat16* ga  = &A[(size_t)(m0 + r0) * 1024 + c0];
    const __hip_bfloat16* gb0 = &Bt[(size_t)(n0 + r0) * 1024 + c0];
    const __hip_bfloat16* gb1 = &Bt[(size_t)(n0 + 64 + r0) * 1024 + c0];
    __hip_bfloat16* la  = &As[(wave * 64) * 8];
    __hip_bfloat16* lb0 = &Bs[(wave * 64) * 8];
    __hip_bfloat16* lb1 = &Bs[(256 + wave * 64) * 8];

    f32x4 acc[2][4];
#pragma unroll
    for (int i = 0; i < 2; ++i)
#pragma unroll
        for (int j = 0; j < 4; ++j) acc[i][j] = (f32x4){0.f, 0.f, 0.f, 0.f};

    for (int k0 = 0; k0 < 1024; k0 += 32) {
        __syncthreads();
        gll16(ga + k0, la);
        gll16(gb0 + k0, lb0);
        gll16(gb1 + k0, lb1);
        __syncthreads();
        short8 af[2], bf4[4];
#pragma unroll
        for (int mt = 0; mt < 2; ++mt)
            af[mt] = *(const short8*)&As[(wr * 32 + mt * 16 + lm) * 32 + quad * 8];
#pragma unroll
        for (int nt = 0; nt < 4; ++nt)
            bf4[nt] = *(const short8*)&Bs[(wc * 64 + nt * 16 + lm) * 32 + quad * 8];
#pragma unroll
        for (int mt = 0; mt < 2; ++mt)
#pragma unroll
            for (int nt = 0; nt < 4; ++nt)
                acc[mt][nt] = __builtin_amdgcn_mfma_f32_16x16x32_bf16(
                    af[mt], bf4[nt], acc[mt][nt], 0, 0, 0);
    }
#pragma unroll
    for (int mt = 0; mt < 2; ++mt)
#pragma unroll
        for (int nt = 0; nt < 4; ++nt) {
            const int col = n0 + wc * 64 + nt * 16 + lm;
#pragma unroll
            for (int i = 0; i < 4; ++i) {
                const int row = m0 + wr * 32 + mt * 16 + quad * 4 + i;
                store_out(&C[(size_t)row * ldc + col], acc[mt][nt][i]);
            }
        }
}

// ---------------------------------------------------------------------------
// sims + topk (unchanged).
// ---------------------------------------------------------------------------
__global__ __launch_bounds__(256) void sims_kernel(const float* __restrict__ lk,
                                                   const float* __restrict__ events,
                                                   float* __restrict__ sims) {
    const int b = blockIdx.y;
    const int tid = threadIdx.x;
    const int wave = tid >> 6, lane = tid & 63;
    __shared__ float qv[1024];
    for (int i = tid; i < 1024; i += 256)
        qv[i] = lk[b * 1024 + i];
    __syncthreads();

    const int m = blockIdx.x * 4 + wave;
    if (m >= MEM_) return;
    const float* ev = &events[(size_t)m * 1024];
    float dot = 0.f, nrm = 0.f;
    for (int d = lane; d < 1024; d += 64) {
        float e = ev[d];
        dot += qv[d] * e;
        nrm += e * e;
    }
    for (int off = 32; off; off >>= 1) {
        dot += __shfl_down(dot, off);
        nrm += __shfl_down(nrm, off);
    }
    if (lane == 0) sims[b * 1024 + m] = dot / (sqrtf(nrm) + 1e-8f);
}

__global__ __launch_bounds__(64) void topk10_kernel(const float* __restrict__ sims,
                                                    int* __restrict__ topk) {
    const int b = blockIdx.x;
    const int lane = threadIdx.x;
    const int base = lane * 16;
    float v[16];
#pragma unroll
    for (int j = 0; j < 16; ++j) {
        const int m = base + j;
        v[j] = (m < MEM_) ? sims[b * 1024 + m] : -INFINITY;
    }
    for (int it = 0; it < KTOT; ++it) {
        float best = -INFINITY; int bi = 0x7fffffff;
#pragma unroll
        for (int j = 0; j < 16; ++j)
            if (v[j] > best) { best = v[j]; bi = base + j; }
        for (int off = 32; off; off >>= 1) {
            const float ob = __shfl_xor(best, off);
            const int   oi = __shfl_xor(bi, off);
            if (ob > best || (ob == best && oi < bi)) { best = ob; bi = oi; }
        }
        if (lane == 0) topk[b * KTOT + it] = bi;
#pragma unroll
        for (int j = 0; j < 16; ++j)
            if (base + j == bi) v[j] = -INFINITY;
    }
}

// ---------------------------------------------------------------------------
// Flash attention R11: intra-block KV split.
// Model (fits R8/R9/R10): kernel is CHAIN-bound on the per-CU LDS pipe —
// R8's 70 us = 33 chain tiles x (3 blocks/CU x 1664 LDS-cyc per block-tile).
// R10's global split-merge died on __threadfence L2 writebacks (FETCH +60%).
// Fix here: split each item's KV range across the block's two WAVE-PAIRS:
//   half A (waves 0,1): mem tile + kt 0..mid-1
//   half B (waves 2,3): kt mid..qt        (mid = (qt+1)>>1)
// Both halves cover the same 64 q-rows, 32 rows/wave -> every Ks/Vt b128
// read feeds 2 MFMAs (2x operand reuse). Each half: own K/V/P/colb LDS
// buffers, own online softmax (m, l via ones-column), own frozen-max
// cutoff (row-independent bound, unchanged math). Merge = one LDS
// exchange at item end (B dumps unnormalized O/m/l into the dead Ks
// region; A rescales, adds, stores) — no global traffic, no fences.
// Chain: 33 -> 17 steps; step advances 2 tiles.
// LDS 58.2 KB -> 2 blocks/CU, grid 512. Softmax in log2 domain via
// __builtin_amdgcn_exp2f.
// ---------------------------------------------------------------------------
__global__ __launch_bounds__(256) void attn_mfma(
        const __hip_bfloat16* __restrict__ qkv,
        const float* __restrict__ events,
        const int* __restrict__ topk,
        const float* __restrict__ amask,
        __hip_bfloat16* __restrict__ out,
        int* __restrict__ ctr) {
    const int tid = threadIdx.x;
    const int wave = tid >> 6, lane = tid & 63;
    const int quad = lane >> 4, lm = lane & 15;
    const int ha = wave >> 1;          // 0 = half A (mem + lower kt), 1 = half B
    const int wp = wave & 1;           // wave within half: rows wp*32 .. +32
    const int htid = tid & 127;        // thread id within half

    const __hip_bfloat16* qf = qkv;
    const __hip_bfloat16* kf = qkv + 1024;
    const __hip_bfloat16* vf = qkv + 2048;

    __shared__ __hip_bfloat16 Ks2[2][64 * LDK];
    __shared__ __hip_bfloat16 Vt2[2][64 * LDK];   // [d][kcol] per half
    __shared__ __hip_bfloat16 Ones[16 * LDK];     // shared l-column tile (row0=1)
    __shared__ __hip_bfloat16 Ps2[2][64 * LDK];
    __shared__ float colb2[2][64];
    __shared__ float redb[4];
    __shared__ int sItem;

    // staging maps (within a half: 128 threads)
    const int krow = htid >> 1, koff = (htid & 1) * 32;
    const int vtok0 = (htid & 15) * 4, vd0 = (htid >> 4) * 8;

    // one-time init: finite fill of Vt (stale x P==0 = 0 needs finite, not
    // NaN) and the static ones tile.
    for (int i = tid * 8; i < 64 * LDK; i += 256 * 8) {
        *(int4*)&Vt2[0][i] = make_int4(0, 0, 0, 0);
        *(int4*)&Vt2[1][i] = make_int4(0, 0, 0, 0);
    }
    for (int i = tid; i < 16 * LDK; i += 256)
        Ones[i] = __float2bfloat16(i < LDK ? 1.0f : 0.0f);

    for (;;) {
        __syncthreads();    // prev item merge-readers done; covers init too
        if (tid == 0) sItem = atomicAdd(ctr, 1);
        __syncthreads();
        const int n = sItem;
        if (n >= NITEMS) break;

        const int qt = 31 - (n >> 5);
        const int q0 = qt * 64;
        const int inner = n & 31;
        const int h = 15 - ((inner >> 1) & 15);
        const int b = inner & 1;
        const float slope2 = __exp2(-0.5f * (float)(h + 1)) * 1.44269504f;
        const int mid = (qt + 1) >> 1;    // A: kt 0..mid-1 ; B: kt mid..qt

        short8 pk[4], pv4[4];
        float pam = 1.f;
        auto prefetchKV = [&](int kt) {
            const __hip_bfloat16* ks =
                &kf[((size_t)(b * S_ + kt * 64 + krow)) * 3072 + h * 64 + koff];
#pragma unroll
            for (int u = 0; u < 4; ++u) pk[u] = *(const short8*)&ks[u * 8];
            const __hip_bfloat16* v0 =
                &vf[((size_t)(b * S_ + kt * 64 + vtok0)) * 3072 + h * 64 + vd0];
#pragma unroll
            for (int t = 0; t < 4; ++t) pv4[t] = *(const short8*)&v0[(size_t)t * 3072];
            if (htid < 64) pam = amask[b * S_ + kt * 64 + htid];
        };
        auto stageKV = [&](int kt) {
#pragma unroll
            for (int u = 0; u < 4; ++u)
                *(short8*)&Ks2[ha][krow * LDK + koff + u * 8] = pk[u];
#pragma unroll
            for (int j = 0; j < 8; ++j) {
                s16x4 w;
                w[0] = pv4[0][j]; w[1] = pv4[1][j]; w[2] = pv4[2][j]; w[3] = pv4[3][j];
                *(s16x4*)&Vt2[ha][(vd0 + j) * LDK + vtok0] = w;
            }
            if (htid < 64)
                colb2[ha][htid] = fmaf(-slope2, (float)(kt * 64 + htid), (1.f - pam) * NEG9);
        };

        // ---- Q fragments, row-shift constants, accumulators ----
        short8 qa[2][2];    // [mt][ks2], rows wp*32 + mt*16 + lm
#pragma unroll
        for (int mt = 0; mt < 2; ++mt) {
            const __hip_bfloat16* qsrc =
                &qf[((size_t)(b * S_ + q0 + wp * 32 + mt * 16 + lm)) * 3072 + h * 64 + quad * 8];
            qa[mt][0] = *(const short8*)qsrc;
            qa[mt][1] = *(const short8*)(qsrc + 32);
        }
        float m_[2][4], mshift[2][4];
        f32x4 Oa[2][5];     // Oa[mt][4] = denominator column
#pragma unroll
        for (int mt = 0; mt < 2; ++mt)
#pragma unroll
            for (int i = 0; i < 4; ++i) {
                m_[mt][i] = -INFINITY;
                mshift[mt][i] = -slope2 * (float)(q0 + wp * 32 + mt * 16 + quad * 4 + i);
                Oa[mt][i] = (f32x4){0.f, 0.f, 0.f, 0.f};
            }
        Oa[0][4] = (f32x4){0.f, 0.f, 0.f, 0.f};
        Oa[1][4] = (f32x4){0.f, 0.f, 0.f, 0.f};

        // mem tile -> half A buffers (cols >= KTOT stale: masked exactly)
        if (tid < 80) {
            const int tok = tid >> 3, d0 = (tid & 7) * 8;
            const int ev = topk[b * KTOT + tok];
            const float* es = &events[(size_t)ev * 1024 + h * 64 + d0];
#pragma unroll
            for (int j = 0; j < 8; ++j) {
                __hip_bfloat16 x = __float2bfloat16(es[j]);
                Ks2[0][tok * LDK + d0 + j] = x;
                Vt2[0][(d0 + j) * LDK + tok] = x;
            }
        }
        // init prefetch: A -> kt0 (if any), B -> mid
        if (ha == 0) { if (mid > 0) prefetchKV(0); }
        else prefetchKV(mid);

        auto computeTile = [&](bool memt, bool online, bool diag, int cbase) {
            f32x4 sa[2][4];
            const __hip_bfloat16* Kp = Ks2[ha];
#pragma unroll
            for (int mt = 0; mt < 2; ++mt)
#pragma unroll
                for (int nt = 0; nt < 4; ++nt) sa[mt][nt] = (f32x4){0.f, 0.f, 0.f, 0.f};
#pragma unroll
            for (int ks2 = 0; ks2 < 2; ++ks2)
#pragma unroll
                for (int nt = 0; nt < 4; ++nt) {
                    short8 bk = *(const short8*)&Kp[(nt * 16 + lm) * LDK + ks2 * 32 + quad * 8];
#pragma unroll
                    for (int mt = 0; mt < 2; ++mt)
                        sa[mt][nt] = __builtin_amdgcn_mfma_f32_16x16x32_bf16(
                            qa[mt][ks2], bk, sa[mt][nt], 0, 0, 0);
                }
            float cb[4];
            if (!memt) {
#pragma unroll
                for (int nt = 0; nt < 4; ++nt) cb[nt] = colb2[ha][nt * 16 + lm];
            }
#pragma unroll
            for (int mt = 0; mt < 2; ++mt)
#pragma unroll
                for (int i = 0; i < 4; ++i) {
                    const int lr = wp * 32 + mt * 16 + quad * 4 + i;
                    const int rg = q0 + lr;
                    float s[4];
#pragma unroll
                    for (int nt = 0; nt < 4; ++nt) {
                        const int cc = nt * 16 + lm;
                        float v;
                        if (memt)
                            v = (cc < KTOT) ? fmaf(sa[mt][nt][i], SC_, mshift[mt][i]) : NEG9;
                        else {
                            v = fmaf(sa[mt][nt][i], SC_, cb[nt]);
                            if (diag && cbase + cc > rg) v = NEG9;
                        }
                        s[nt] = v;
                    }
                    float cm;
                    if (online) {
                        float rmax = fmaxf(fmaxf(s[0], s[1]), fmaxf(s[2], s[3]));
#pragma unroll
                        for (int off = 1; off < 16; off <<= 1)
                            rmax = fmaxf(rmax, __shfl_xor(rmax, off, 16));
                        const float newm = fmaxf(m_[mt][i], rmax);
                        const float al = __exp2(m_[mt][i] - newm);
                        m_[mt][i] = newm; cm = newm;
#pragma unroll
                        for (int nt = 0; nt < 5; ++nt) Oa[mt][nt][i] *= al;
                    } else cm = m_[mt][i];
#pragma unroll
                    for (int nt = 0; nt < 4; ++nt)
                        Ps2[ha][lr * LDK + nt * 16 + lm] = __float2bfloat16(__exp2(s[nt] - cm));
                }
            // PV
#pragma unroll
            for (int ks2 = 0; ks2 < 2; ++ks2) {
                short8 ap0 = *(const short8*)&Ps2[ha][(wp * 32 + lm) * LDK + ks2 * 32 + quad * 8];
                short8 ap1 = *(const short8*)&Ps2[ha][(wp * 32 + 16 + lm) * LDK + ks2 * 32 + quad * 8];
#pragma unroll
                for (int nt = 0; nt < 4; ++nt) {
                    short8 bv = *(const short8*)&Vt2[ha][(nt * 16 + lm) * LDK + ks2 * 32 + quad * 8];
                    Oa[0][nt] = __builtin_amdgcn_mfma_f32_16x16x32_bf16(ap0, bv, Oa[0][nt], 0, 0, 0);
                    Oa[1][nt] = __builtin_amdgcn_mfma_f32_16x16x32_bf16(ap1, bv, Oa[1][nt], 0, 0, 0);
                }
                short8 bvO = *(const short8*)&Ones[lm * LDK + ks2 * 32 + quad * 8];
                Oa[0][4] = __builtin_amdgcn_mfma_f32_16x16x32_bf16(ap0, bvO, Oa[0][4], 0, 0, 0);
                Oa[1][4] = __builtin_amdgcn_mfma_f32_16x16x32_bf16(ap1, bvO, Oa[1][4], 0, 0, 0);
            }
        };
        auto redbWrite = [&]() {
            float mloc = fminf(fminf(m_[0][0], m_[0][1]), fminf(m_[0][2], m_[0][3]));
            mloc = fminf(mloc, fminf(fminf(m_[1][0], m_[1][1]), fminf(m_[1][2], m_[1][3])));
#pragma unroll
            for (int off = 1; off < 64; off <<= 1)
                mloc = fminf(mloc, __shfl_xor(mloc, off, 64));
            if (lane == 0) redb[wave] = mloc;
        };

        // ================= step 0 =================
        if (ha == 1) {                       // B stages its first tile
            stageKV(mid);
            if (mid + 1 <= qt) prefetchKV(mid + 1);
        }
        __syncthreads();                     // publish mem (A) + tile mid (B)
        if (ha == 0) {
            computeTile(true, true, false, 0);
        } else {
            computeTile(false, true, mid == qt, mid * 64);
            redbWrite();                     // -> redb[2],redb[3]
        }

        // ================= step 1 =================
        __syncthreads();                     // compute done; redb[2..3] visible
        const int kendB = max(mid, min(qt,
            (int)((TH_ - fminf(redb[2], redb[3])) / (64.f * slope2))));
        if (ha == 0) {
            if (mid > 0) { stageKV(0); if (1 <= mid - 1) prefetchKV(1); }
        } else {
            if (mid + 1 <= kendB) stageKV(mid + 1);
            if (mid + 2 <= kendB) prefetchKV(mid + 2);
        }
        __syncthreads();
        if (ha == 0) {
            if (mid > 0) { computeTile(false, true, false, 0); redbWrite(); } // redb[0..1]
        } else if (mid + 1 <= kendB) {
            computeTile(false, false, (mid + 1) == qt, (mid + 1) * 64);
        }

        // ================= steps >= 2 =================
        int kendA = -1, smax = 2;
        for (int s = 2;; ++s) {
            __syncthreads();                 // compute done; (s==2) redb[0..1]
            if (s == 2) {
                if (mid > 0)
                    kendA = min(mid - 1, max(0,
                        (int)((TH_ - fminf(redb[0], redb[1])) / (64.f * slope2))));
                smax = max(kendA + 2, kendB - mid + 1);
            }
            if (s >= smax) break;
            if (ha == 0) {
                if (s - 1 <= kendA) stageKV(s - 1);
                if (s <= kendA) prefetchKV(s);
            } else {
                if (mid + s <= kendB) stageKV(mid + s);
                if (mid + s + 1 <= kendB) prefetchKV(mid + s + 1);
            }
            __syncthreads();
            if (ha == 0) {
                if (s - 1 <= kendA) computeTile(false, false, false, (s - 1) * 64);
            } else if (mid + s <= kendB) {
                computeTile(false, false, (mid + s) == qt, (mid + s) * 64);
            }
        }

        // ================= merge (LDS, no global) =================
        float l_[2][4];
#pragma unroll
        for (int mt = 0; mt < 2; ++mt)
#pragma unroll
            for (int i = 0; i < 4; ++i) l_[mt][i] = __shfl(Oa[mt][4][i], (lane & 48));

        float* mO = (float*)Ks2;             // 16 KB overlay (Ks dead now)
        float* mM = colb2[0];
        float* mL = colb2[1];
        if (ha == 1) {
#pragma unroll
            for (int mt = 0; mt < 2; ++mt)
#pragma unroll
                for (int i = 0; i < 4; ++i) {
                    const int lr = wp * 32 + mt * 16 + quad * 4 + i;
#pragma unroll
                    for (int nt = 0; nt < 4; ++nt)
                        mO[lr * 64 + nt * 16 + lm] = Oa[mt][nt][i];
                    if (lm == 0) { mM[lr] = m_[mt][i]; mL[lr] = l_[mt][i]; }
                }
        }
        __syncthreads();
        if (ha == 0) {
#pragma unroll
            for (int mt = 0; mt < 2; ++mt)
#pragma unroll
                for (int i = 0; i < 4; ++i) {
                    const int lr = wp * 32 + mt * 16 + quad * 4 + i;
                    const float mB = mM[lr], lB = mL[lr];
                    const float mA = m_[mt][i], lA = l_[mt][i];
                    const float mm = fmaxf(mA, mB);
                    const float fA = __exp2(mA - mm), fB = __exp2(mB - mm);
                    const float inv = 1.f / (lA * fA + lB * fB);
                    __hip_bfloat16* dst =
                        &out[((size_t)(b * S_ + q0 + lr)) * 1024 + h * 64 + lm];
#pragma unroll
                    for (int nt = 0; nt < 4; ++nt)
                        dst[nt * 16] = __float2bfloat16(
                            (Oa[mt][nt][i] * fA + mO[lr * 64 + nt * 16 + lm] * fB) * inv);
                }
        }
    }
}

// ---------------------------------------------------------------------------
extern "C" void kernel_launch(void* const* d_in, const int* in_sizes, int n_in,
                              void* d_out, int out_size, void* d_ws, size_t ws_size,
                              hipStream_t stream) {
    const float* inputs = (const float*)d_in[0];
    const float* amask  = (const float*)d_in[1];
    const float* Wq     = (const float*)d_in[2];
    const float* Wk     = (const float*)d_in[3];
    const float* Wv     = (const float*)d_in[4];
    const float* Wo     = (const float*)d_in[5];
    const float* events = (const float*)d_in[6];
    float* out = (float*)d_out;

    // ws: Ax 8MB | Wt 8MB | qkv 24MB | ao 8MB | lk | sims | topk | ctr
    __hip_bfloat16* Ax  = (__hip_bfloat16*)d_ws;
    __hip_bfloat16* Wt  = Ax + (size_t)NROW * 1024;
    __hip_bfloat16* qkv = Wt + (size_t)4096 * 1024;
    __hip_bfloat16* ao  = qkv + (size_t)NROW * 3072;
    float* lk   = (float*)(ao + (size_t)NROW * 1024);
    float* sims = lk + 2 * 1024;
    int* topk   = (int*)(sims + 2 * 1024);
    int* ctr    = topk + B_ * KTOT;

    dim3 blk(256);
    prep<<<3104, blk, 0, stream>>>(inputs, Wq, Wk, Wv, Wo, Ax, Wt, lk, ctr);
    sims_kernel<<<dim3(250, B_), blk, 0, stream>>>(lk, events, sims);
    topk10_kernel<<<B_, 64, 0, stream>>>(sims, topk);
    gemm_mfma<__hip_bfloat16><<<dim3(24, 32), blk, 0, stream>>>(Ax, Wt, qkv, 3072);
    attn_mfma<<<512, blk, 0, stream>>>(qkv, events, topk, amask, ao, ctr);
    gemm_mfma64<float><<<dim3(8, 64), blk, 0, stream>>>(
        ao, Wt + (size_t)3072 * 1024, out, 1024);
}

// Round 4
// 255.634 us; speedup vs baseline: 1.5004x; 1.0664x over previous
//
#include <hip/hip_runtime.h>
#include <hip/hip_bf16.h>
#include <math.h>

// Problem constants
#define B_   2
#define S_   2048
#define DM_  1024
#define H_   16
#define HD_  64
#define MEM_ 1000
#define KTOT 10
#define NROW (B_ * S_)          // 4096
#define NEG9 (-1e9f)
#define LDK  72                 // bf16 row stride in attention LDS tiles

// R12 decomposition: items with qt>=19 split into 2 KV-halves processed by
// INDEPENDENT blocks; fence-free partial dump + separate merge kernel.
#define NUNITS  1440            // 832 split halves + 608 unsplit items
#define NSPLITI 416             // split items (qt 19..31) x 32 (h,b)
#define PSLOT   4224            // floats per partial slot: 64x64 O + 64 m + 64 l
#define SC_  0.18033688f        // 0.125 * log2(e)  (QK scale, log2 domain)
#define TH_  170.238f           // 118 * log2(e)    (exact-underflow cutoff)

typedef __attribute__((ext_vector_type(8))) short short8;
typedef __attribute__((ext_vector_type(4))) float f32x4;

__device__ __forceinline__ float __exp2(float x) { return __builtin_amdgcn_exp2f(x); }

// async global->LDS, 16B per lane, dest = wave-uniform base + lane*16
__device__ __forceinline__ void gll16(const __hip_bfloat16* g, __hip_bfloat16* l) {
    __builtin_amdgcn_global_load_lds(
        (const __attribute__((address_space(1))) void*)g,
        (__attribute__((address_space(3))) void*)l, 16, 0, 0);
}

// ---------------------------------------------------------------------------
// prep: fused prologue (independent parts, branch on block range).
// ---------------------------------------------------------------------------
__global__ __launch_bounds__(256) void prep(const float* __restrict__ inputs,
                                            const float* __restrict__ Wq,
                                            const float* __restrict__ Wk,
                                            const float* __restrict__ Wv,
                                            const float* __restrict__ Wo,
                                            __hip_bfloat16* __restrict__ Ax,
                                            __hip_bfloat16* __restrict__ Wt,
                                            float* __restrict__ lk,
                                            int* __restrict__ ctr) {
    const int bx = blockIdx.x, tid = threadIdx.x;
    if (bx == 0 && tid == 0) *ctr = 0;

    if (bx < 2048) {
        const size_t i = ((size_t)bx * 256 + tid) * 8;
        float4 a = *(const float4*)&inputs[i];
        float4 b = *(const float4*)&inputs[i + 4];
        alignas(16) __hip_bfloat16 t[8];
        t[0] = __float2bfloat16(a.x); t[1] = __float2bfloat16(a.y);
        t[2] = __float2bfloat16(a.z); t[3] = __float2bfloat16(a.w);
        t[4] = __float2bfloat16(b.x); t[5] = __float2bfloat16(b.y);
        t[6] = __float2bfloat16(b.z); t[7] = __float2bfloat16(b.w);
        *(short8*)&Ax[i] = *(short8*)t;
        return;
    }
    if (bx < 3072) {
        const int idx = bx - 2048;
        const int g = idx >> 8, rem = idx & 255;
        const float* W = (g == 0) ? Wq : (g == 1) ? Wk : (g == 2) ? Wv : Wo;
        const int n0 = (rem & 15) * 64, k0 = (rem >> 4) * 64;
        __shared__ float T[64][65];
        {
            const int r = tid >> 4, c4 = (tid & 15) * 4;
#pragma unroll
            for (int p = 0; p < 4; ++p) {
                float4 v = *(const float4*)&W[(size_t)(k0 + r + p * 16) * 1024 + n0 + c4];
                T[r + p * 16][c4 + 0] = v.x; T[r + p * 16][c4 + 1] = v.y;
                T[r + p * 16][c4 + 2] = v.z; T[r + p * 16][c4 + 3] = v.w;
            }
        }
        __syncthreads();
        {
            const int n = tid >> 3, off = (tid & 7) * 8;
#pragma unroll
            for (int p = 0; p < 2; ++p) {
                const int nn = n + p * 32;
                alignas(16) __hip_bfloat16 t[8];
#pragma unroll
                for (int j = 0; j < 8; ++j) t[j] = __float2bfloat16(T[off + j][nn]);
                *(short8*)&Wt[((size_t)(g * 1024 + n0 + nn)) * 1024 + k0 + off] = *(short8*)t;
            }
        }
        return;
    }
    {   // lastk: lk[b,:] = inputs[b, S-1, :] @ Wk (fp32)
        const int idx = bx - 3072;
        const int xblk = idx & 15, b = idx >> 4;
        const int cl = tid & 63;
        const int col = xblk * 64 + cl;
        const int kq = tid >> 6;
        __shared__ float xr[1024];
        __shared__ float part[4][64];
        for (int i = tid; i < 1024; i += 256)
            xr[i] = inputs[((size_t)(b * S_ + S_ - 1)) * 1024 + i];
        __syncthreads();
        float acc = 0.f;
#pragma unroll 4
        for (int k = kq * 256; k < kq * 256 + 256; ++k)
            acc += xr[k] * Wk[(size_t)k * 1024 + col];
        part[kq][cl] = acc;
        __syncthreads();
        if (tid < 64)
            lk[b * 1024 + xblk * 64 + tid] =
                part[0][tid] + part[1][tid] + part[2][tid] + part[3][tid];
    }
}

// ---------------------------------------------------------------------------
// bf16 MFMA GEMM, m97 structure (unchanged, proven).
// ---------------------------------------------------------------------------
__device__ __forceinline__ void store_out(__hip_bfloat16* p, float x) { *p = __float2bfloat16(x); }
__device__ __forceinline__ void store_out(float* p, float x) { *p = x; }

template <typename OutT>
__global__ __launch_bounds__(256) void gemm_mfma(const __hip_bfloat16* __restrict__ A,
                                                 const __hip_bfloat16* __restrict__ Bt,
                                                 OutT* __restrict__ C, int ldc) {
    __shared__ __hip_bfloat16 As[128 * 32];
    __shared__ __hip_bfloat16 Bs[128 * 32];
    const int tid = threadIdx.x;
    const int wave = tid >> 6, lane = tid & 63;
    const int quad = lane >> 4, lm = lane & 15;
    const int wr = wave >> 1, wc = wave & 1;
    const int m0 = blockIdx.y * 128, n0 = blockIdx.x * 128;

    const int r0 = tid >> 2, c0 = (tid & 3) * 8;
    const __hip_bfloat16* ga0 = &A[(size_t)(m0 + r0) * 1024 + c0];
    const __hip_bfloat16* ga1 = &A[(size_t)(m0 + 64 + r0) * 1024 + c0];
    const __hip_bfloat16* gb0 = &Bt[(size_t)(n0 + r0) * 1024 + c0];
    const __hip_bfloat16* gb1 = &Bt[(size_t)(n0 + 64 + r0) * 1024 + c0];
    __hip_bfloat16* la0 = &As[(wave * 64) * 8];
    __hip_bfloat16* la1 = &As[(256 + wave * 64) * 8];
    __hip_bfloat16* lb0 = &Bs[(wave * 64) * 8];
    __hip_bfloat16* lb1 = &Bs[(256 + wave * 64) * 8];

    f32x4 acc[4][4];
#pragma unroll
    for (int i = 0; i < 4; ++i)
#pragma unroll
        for (int j = 0; j < 4; ++j) acc[i][j] = (f32x4){0.f, 0.f, 0.f, 0.f};

    for (int k0 = 0; k0 < 1024; k0 += 32) {
        __syncthreads();
        gll16(ga0 + k0, la0);
        gll16(ga1 + k0, la1);
        gll16(gb0 + k0, lb0);
        gll16(gb1 + k0, lb1);
        __syncthreads();
        short8 af[4], bf4[4];
#pragma unroll
        for (int mt = 0; mt < 4; ++mt)
            af[mt] = *(const short8*)&As[(wr * 64 + mt * 16 + lm) * 32 + quad * 8];
#pragma unroll
        for (int nt = 0; nt < 4; ++nt)
            bf4[nt] = *(const short8*)&Bs[(wc * 64 + nt * 16 + lm) * 32 + quad * 8];
#pragma unroll
        for (int mt = 0; mt < 4; ++mt)
#pragma unroll
            for (int nt = 0; nt < 4; ++nt)
                acc[mt][nt] = __builtin_amdgcn_mfma_f32_16x16x32_bf16(
                    af[mt], bf4[nt], acc[mt][nt], 0, 0, 0);
    }
#pragma unroll
    for (int mt = 0; mt < 4; ++mt)
#pragma unroll
        for (int nt = 0; nt < 4; ++nt) {
            const int col = n0 + wc * 64 + nt * 16 + lm;
#pragma unroll
            for (int i = 0; i < 4; ++i) {
                const int row = m0 + wr * 64 + mt * 16 + quad * 4 + i;
                store_out(&C[(size_t)row * ldc + col], acc[mt][nt][i]);
            }
        }
}

// ---------------------------------------------------------------------------
// 64x128-tile variant for the out-projection GEMM (R9 win, kept).
// ---------------------------------------------------------------------------
template <typename OutT>
__global__ __launch_bounds__(256) void gemm_mfma64(const __hip_bfloat16* __restrict__ A,
                                                   const __hip_bfloat16* __restrict__ Bt,
                                                   OutT* __restrict__ C, int ldc) {
    __shared__ __hip_bfloat16 As[64 * 32];
    __shared__ __hip_bfloat16 Bs[128 * 32];
    const int tid = threadIdx.x;
    const int wave = tid >> 6, lane = tid & 63;
    const int quad = lane >> 4, lm = lane & 15;
    const int wr = wave >> 1, wc = wave & 1;
    const int m0 = blockIdx.y * 64, n0 = blockIdx.x * 128;

    const int r0 = tid >> 2, c0 = (tid & 3) * 8;
    const __hip_bfloat16* ga  = &A[(size_t)(m0 + r0) * 1024 + c0];
    const __hip_bfloat16* gb0 = &Bt[(size_t)(n0 + r0) * 1024 + c0];
    const __hip_bfloat16* gb1 = &Bt[(size_t)(n0 + 64 + r0) * 1024 + c0];
    __hip_bfloat16* la  = &As[(wave * 64) * 8];
    __hip_bfloat16* lb0 = &Bs[(wave * 64) * 8];
    __hip_bfloat16* lb1 = &Bs[(256 + wave * 64) * 8];

    f32x4 acc[2][4];
#pragma unroll
    for (int i = 0; i < 2; ++i)
#pragma unroll
        for (int j = 0; j < 4; ++j) acc[i][j] = (f32x4){0.f, 0.f, 0.f, 0.f};

    for (int k0 = 0; k0 < 1024; k0 += 32) {
        __syncthreads();
        gll16(ga + k0, la);
        gll16(gb0 + k0, lb0);
        gll16(gb1 + k0, lb1);
        __syncthreads();
        short8 af[2], bf4[4];
#pragma unroll
        for (int mt = 0; mt < 2; ++mt)
            af[mt] = *(const short8*)&As[(wr * 32 + mt * 16 + lm) * 32 + quad * 8];
#pragma unroll
        for (int nt = 0; nt < 4; ++nt)
            bf4[nt] = *(const short8*)&Bs[(wc * 64 + nt * 16 + lm) * 32 + quad * 8];
#pragma unroll
        for (int mt = 0; mt < 2; ++mt)
#pragma unroll
            for (int nt = 0; nt < 4; ++nt)
                acc[mt][nt] = __builtin_amdgcn_mfma_f32_16x16x32_bf16(
                    af[mt], bf4[nt], acc[mt][nt], 0, 0, 0);
    }
#pragma unroll
    for (int mt = 0; mt < 2; ++mt)
#pragma unroll
        for (int nt = 0; nt < 4; ++nt) {
            const int col = n0 + wc * 64 + nt * 16 + lm;
#pragma unroll
            for (int i = 0; i < 4; ++i) {
                const int row = m0 + wr * 32 + mt * 16 + quad * 4 + i;
                store_out(&C[(size_t)row * ldc + col], acc[mt][nt][i]);
            }
        }
}

// ---------------------------------------------------------------------------
// sims + topk (unchanged).
// ---------------------------------------------------------------------------
__global__ __launch_bounds__(256) void sims_kernel(const float* __restrict__ lk,
                                                   const float* __restrict__ events,
                                                   float* __restrict__ sims) {
    const int b = blockIdx.y;
    const int tid = threadIdx.x;
    const int wave = tid >> 6, lane = tid & 63;
    __shared__ float qv[1024];
    for (int i = tid; i < 1024; i += 256)
        qv[i] = lk[b * 1024 + i];
    __syncthreads();

    const int m = blockIdx.x * 4 + wave;
    if (m >= MEM_) return;
    const float* ev = &events[(size_t)m * 1024];
    float dot = 0.f, nrm = 0.f;
    for (int d = lane; d < 1024; d += 64) {
        float e = ev[d];
        dot += qv[d] * e;
        nrm += e * e;
    }
    for (int off = 32; off; off >>= 1) {
        dot += __shfl_down(dot, off);
        nrm += __shfl_down(nrm, off);
    }
    if (lane == 0) sims[b * 1024 + m] = dot / (sqrtf(nrm) + 1e-8f);
}

__global__ __launch_bounds__(64) void topk10_kernel(const float* __restrict__ sims,
                                                    int* __restrict__ topk) {
    const int b = blockIdx.x;
    const int lane = threadIdx.x;
    const int base = lane * 16;
    float v[16];
#pragma unroll
    for (int j = 0; j < 16; ++j) {
        const int m = base + j;
        v[j] = (m < MEM_) ? sims[b * 1024 + m] : -INFINITY;
    }
    for (int it = 0; it < KTOT; ++it) {
        float best = -INFINITY; int bi = 0x7fffffff;
#pragma unroll
        for (int j = 0; j < 16; ++j)
            if (v[j] > best) { best = v[j]; bi = base + j; }
        for (int off = 32; off; off >>= 1) {
            const float ob = __shfl_xor(best, off);
            const int   oi = __shfl_xor(bi, off);
            if (ob > best || (ob == best && oi < bi)) { best = ob; bi = oi; }
        }
        if (lane == 0) topk[b * KTOT + it] = bi;
#pragma unroll
        for (int j = 0; j < 16; ++j)
            if (base + j == bi) v[j] = -INFINITY;
    }
}

// ---------------------------------------------------------------------------
// Flash attention R12 = EXACT R8 tile engine (70.2 us, best measured:
// single-buffer LDS, 2 barriers/tile, reg prefetch, ones-column l-accum,
// frozen-max cutoff) + fence-free cross-block KV split:
//  * items with qt>=19 are TWO independent work units (lower = mem + kt
//    0..mid-1, upper = kt mid..qt; mid=(qt+1)>>1), each running the R8 loop
//    with its own online softmax. Halves write unnormalized O + per-row
//    (m,l) to global partial slots with PLAIN stores — no fence, no atomic,
//    no in-kernel merge (R10's __threadfence L2-writeback disaster avoided).
//    A separate merge kernel (after attn) combines halves; the kernel
//    boundary provides ordering.
//  * 1440 units in ~LPT order; longest chain 33 -> 20 tiles. Grid 1024
//    (4 blocks/CU by LDS 30.7 KB).
//  * softmax in log2 domain (proven R10/R11).
// ---------------------------------------------------------------------------
__global__ __launch_bounds__(256) void attn_mfma(
        const __hip_bfloat16* __restrict__ qkv,
        const float* __restrict__ events,
        const int* __restrict__ topk,
        const float* __restrict__ amask,
        __hip_bfloat16* __restrict__ out,
        int* __restrict__ ctr,
        float* __restrict__ partb) {
    const int tid = threadIdx.x;
    const int wave = tid >> 6, lane = tid & 63;
    const int quad = lane >> 4, lm = lane & 15;

    const __hip_bfloat16* qf = qkv;
    const __hip_bfloat16* kf = qkv + 1024;
    const __hip_bfloat16* vf = qkv + 2048;

    __shared__ __hip_bfloat16 Ks[64 * LDK];
    __shared__ __hip_bfloat16 Vt[80 * LDK];   // [d][kcol]; rows 64..79 static (64=ones)
    __shared__ __hip_bfloat16 Ps[64 * LDK];
    __shared__ float colb[64];
    __shared__ float redb[4];
    __shared__ int sItem;

    const int va = tid & 31, vdc = tid >> 5;
    const int vtok0 = va * 2, vd0 = vdc * 8;

    // one-time init: finite Vt fill (stale x P==0 = 0 needs finite, not NaN)
    // and the static ones/zero rows.
    for (int i = tid * 8; i < 64 * LDK; i += 256 * 8)
        *(int4*)&Vt[i] = make_int4(0, 0, 0, 0);
    for (int i = tid; i < 16 * LDK; i += 256) {
        const int r = i / LDK;
        Vt[64 * LDK + i] = __float2bfloat16(r == 0 ? 1.0f : 0.0f);
    }

    for (;;) {
        __syncthreads();    // prev item's LDS readers done; also covers Vt init
        if (tid == 0) sItem = atomicAdd(ctr, 1);
        __syncthreads();
        const int n = sItem;
        if (n >= NUNITS) break;

        // ---- unit decode (~LPT order; see launcher comment) ----
        int qt, inner, kstart, kend, prt = 0, sidx = 0;
        bool haveMem, split;
        {
            int sel;
            if (n < 96)        { qt = 18 - (n >> 5); inner = n & 31; sel = 2; }
            else if (n < 160)  { const int m = n - 96; inner = m & 31;
                                 if (m < 32) { qt = 31; sel = 0; } else { qt = 15; sel = 2; } }
            else if (n < 288)  { const int m = n - 160; const int s4 = m >> 5; inner = m & 31;
                                 if (s4 == 0)      { qt = 31; sel = 1; }
                                 else if (s4 == 1) { qt = 30; sel = 0; }
                                 else if (s4 == 2) { qt = 30; sel = 1; }
                                 else              { qt = 14; sel = 2; } }
            else if (n < 1344) { const int m = n - 288; const int g = m / 96, r = m - g * 96;
                                 sel = r >> 5; inner = r & 31;
                                 qt = (sel < 2) ? (29 - g) : (13 - g); }
            else               { const int m = n - 1344; qt = 2 - (m >> 5); inner = m & 31; sel = 2; }
            if (sel == 2) { kstart = 0; kend = qt; haveMem = true; split = false; }
            else {
                const int mid = (qt + 1) >> 1;
                prt = sel;
                kstart = prt ? mid : 0;
                kend   = prt ? qt : (mid - 1);
                haveMem = (prt == 0);
                split = true;
                sidx = (31 - qt) * 32 + inner;
            }
        }
        const int q0 = qt * 64;
        const int h = 15 - ((inner >> 1) & 15);
        const int b = inner & 1;
        const float slope2 = __exp2(-0.5f * (float)(h + 1)) * 1.44269504f;  // log2 dom

        short8 pk[2], pv0, pv1;
        float pam = 1.f;
        auto prefetchKV = [&](int kt) {
            const __hip_bfloat16* ks = &kf[((size_t)(b * S_ + kt * 64)) * 3072 + h * 64];
#pragma unroll
            for (int u = 0; u < 2; ++u) {
                int c = tid * 2 + u, row = c >> 3, off = (c & 7) * 8;
                pk[u] = *(const short8*)&ks[(size_t)row * 3072 + off];
            }
            const __hip_bfloat16* v0 =
                &vf[((size_t)(b * S_ + kt * 64 + vtok0)) * 3072 + h * 64 + vd0];
            pv0 = *(const short8*)v0;
            pv1 = *(const short8*)(v0 + 3072);
            if (tid < 64) pam = amask[b * S_ + kt * 64 + tid];
        };
        auto stageKV = [&](int kt) {
#pragma unroll
            for (int u = 0; u < 2; ++u) {
                int c = tid * 2 + u, row = c >> 3, off = (c & 7) * 8;
                *(short8*)&Ks[row * LDK + off] = pk[u];
            }
#pragma unroll
            for (int j = 0; j < 8; ++j) {
                short2 pr; pr.x = pv0[j]; pr.y = pv1[j];
                *(short2*)&Vt[(vd0 + j) * LDK + vtok0] = pr;
            }
            if (tid < 64)
                colb[tid] = fmaf(-slope2, (float)(kt * 64 + tid), (1.f - pam) * NEG9);
        };

        prefetchKV(kstart);     // earliest possible issue

        // ---- Q fragments straight into registers ----
        short8 qa[2];
        {
            const __hip_bfloat16* qsrc =
                &qf[((size_t)(b * S_ + q0 + wave * 16 + lm)) * 3072 + h * 64 + quad * 8];
            qa[0] = *(const short8*)qsrc;
            qa[1] = *(const short8*)(qsrc + 32);
        }
        // memory tile (K rows 0..9; Vt cols 0..9; stale rest exactly masked)
        if (haveMem && tid < 80) {
            const int tok = tid >> 3, d0 = (tid & 7) * 8;
            const int ev = topk[b * KTOT + tok];
            const float* es = &events[(size_t)ev * 1024 + h * 64 + d0];
#pragma unroll
            for (int j = 0; j < 8; ++j) {
                __hip_bfloat16 x = __float2bfloat16(es[j]);
                Ks[tok * LDK + d0 + j] = x;
                Vt[(d0 + j) * LDK + tok] = x;
            }
        }

        float m_[4], mshift[4];
        f32x4 Oa[5];        // Oa[4] = softmax denominator column
#pragma unroll
        for (int i = 0; i < 4; ++i) {
            m_[i] = -INFINITY;
            mshift[i] = -slope2 * (float)(q0 + wave * 16 + quad * 4 + i);
        }
#pragma unroll
        for (int nt = 0; nt < 5; ++nt) Oa[nt] = (f32x4){0.f, 0.f, 0.f, 0.f};

        auto qk = [&](f32x4* sa) {
#pragma unroll
            for (int nt = 0; nt < 4; ++nt) sa[nt] = (f32x4){0.f, 0.f, 0.f, 0.f};
#pragma unroll
            for (int ks2 = 0; ks2 < 2; ++ks2) {
#pragma unroll
                for (int nt = 0; nt < 4; ++nt) {
                    short8 bk = *(const short8*)&Ks[(nt * 16 + lm) * LDK + ks2 * 32 + quad * 8];
                    sa[nt] = __builtin_amdgcn_mfma_f32_16x16x32_bf16(qa[ks2], bk, sa[nt], 0, 0, 0);
                }
            }
        };
        auto pv = [&]() {
#pragma unroll
            for (int ks2 = 0; ks2 < 2; ++ks2) {
                short8 ap = *(const short8*)&Ps[(wave * 16 + lm) * LDK + ks2 * 32 + quad * 8];
#pragma unroll
                for (int nt = 0; nt < 5; ++nt) {   // nt=4: ones column -> l
                    short8 bv = *(const short8*)&Vt[(nt * 16 + lm) * LDK + ks2 * 32 + quad * 8];
                    Oa[nt] = __builtin_amdgcn_mfma_f32_16x16x32_bf16(ap, bv, Oa[nt], 0, 0, 0);
                }
            }
        };

        auto softmax_online = [&](const f32x4* sa, int kt, bool diag) {
            float cb[4];
            if (kt >= 0) {
#pragma unroll
                for (int nt = 0; nt < 4; ++nt) cb[nt] = colb[nt * 16 + lm];
            }
#pragma unroll
            for (int i = 0; i < 4; ++i) {
                const int lr = wave * 16 + quad * 4 + i;
                const int rg = q0 + lr;
                float s[4];
#pragma unroll
                for (int nt = 0; nt < 4; ++nt) {
                    const int cc = nt * 16 + lm;
                    if (kt < 0) {
                        s[nt] = (cc < KTOT) ? fmaf(sa[nt][i], SC_, mshift[i]) : NEG9;
                    } else {
                        float v = fmaf(sa[nt][i], SC_, cb[nt]);
                        s[nt] = (diag && kt * 64 + cc > rg) ? NEG9 : v;
                    }
                }
                float rmax = fmaxf(fmaxf(s[0], s[1]), fmaxf(s[2], s[3]));
#pragma unroll
                for (int off = 1; off < 16; off <<= 1)
                    rmax = fmaxf(rmax, __shfl_xor(rmax, off, 16));
                const float newm = fmaxf(m_[i], rmax);
                const float al = __exp2(m_[i] - newm);
                m_[i] = newm;
#pragma unroll
                for (int nt = 0; nt < 4; ++nt)
                    Ps[lr * LDK + nt * 16 + lm] = __float2bfloat16(__exp2(s[nt] - newm));
#pragma unroll
                for (int nt = 0; nt < 5; ++nt)     // includes l-column
                    Oa[nt][i] *= al;
            }
        };

        auto softmax_fast = [&](const f32x4* sa, int cbase, bool diag) {
            float cb[4];
#pragma unroll
            for (int nt = 0; nt < 4; ++nt) cb[nt] = colb[nt * 16 + lm];
#pragma unroll
            for (int i = 0; i < 4; ++i) {
                const int lr = wave * 16 + quad * 4 + i;
                const float cm = m_[i];
                float p[4];
#pragma unroll
                for (int nt = 0; nt < 4; ++nt)
                    p[nt] = __exp2(fmaf(sa[nt][i], SC_, cb[nt]) - cm);
                if (diag) {
                    const int rg = q0 + lr;
#pragma unroll
                    for (int nt = 0; nt < 4; ++nt)
                        if (cbase + nt * 16 + lm > rg) p[nt] = 0.f;
                }
#pragma unroll
                for (int nt = 0; nt < 4; ++nt)
                    Ps[lr * LDK + nt * 16 + lm] = __float2bfloat16(p[nt]);
            }
        };

        // ---- memory tile (online) ----
        if (haveMem) {
            __syncthreads();        // publish mem tile
            f32x4 sa[4];
            qk(sa);
            softmax_online(sa, -1, false);
            pv();
            __syncthreads();        // mem readers done before stage overwrites
        }
        // ---- first regular tile kt = kstart (online) ----
        stageKV(kstart);
        if (kstart < kend) prefetchKV(kstart + 1);
        __syncthreads();
        {
            f32x4 sa[4];
            qk(sa);
            softmax_online(sa, kstart, kstart == qt);
            pv();
        }

        // ---- freeze max; block-min(m) -> exact-underflow cutoff ----
        int kend2 = kstart;
        if (kend > kstart) {
            float mloc = fminf(fminf(m_[0], m_[1]), fminf(m_[2], m_[3]));
#pragma unroll
            for (int off = 1; off < 64; off <<= 1)
                mloc = fminf(mloc, __shfl_xor(mloc, off, 64));
            if (lane == 0) redb[wave] = mloc;
            __syncthreads();        // redb visible + first-tile readers done
            const float mmin = fminf(fminf(redb[0], redb[1]), fminf(redb[2], redb[3]));
            kend2 = min(kend, (int)((TH_ - mmin) / (64.f * slope2)));
        }
        for (int kt = kstart + 1; kt <= kend2; ++kt) {
            __syncthreads();
            stageKV(kt);
            if (kt < kend2) prefetchKV(kt + 1);
            __syncthreads();
            f32x4 sa[4];
            qk(sa);
            softmax_fast(sa, kt * 64, kt == qt);
            pv();
        }

        // ---- epilogue ----
        float l_[4];
#pragma unroll
        for (int i = 0; i < 4; ++i) l_[i] = __shfl(Oa[4][i], (lane & 48));
        if (!split) {
#pragma unroll
            for (int i = 0; i < 4; ++i) {
                const int lr = wave * 16 + quad * 4 + i;
                const float inv = 1.f / l_[i];
                __hip_bfloat16* dst = &out[((size_t)(b * S_ + q0 + lr)) * 1024 + h * 64 + lm];
#pragma unroll
                for (int nt = 0; nt < 4; ++nt)
                    dst[nt * 16] = __float2bfloat16(Oa[nt][i] * inv);
            }
        } else {
            // plain partial dump; merge happens in a later kernel (no fence)
            float* psl = partb + (size_t)(sidx * 2 + prt) * PSLOT;
#pragma unroll
            for (int i = 0; i < 4; ++i) {
                const int lr = wave * 16 + quad * 4 + i;
#pragma unroll
                for (int nt = 0; nt < 4; ++nt)
                    psl[lr * 64 + nt * 16 + lm] = Oa[nt][i];
                if (lm == 0) {
                    psl[4096 + lr] = m_[i];
                    psl[4160 + lr] = l_[i];
                }
            }
        }
    }
}

// ---------------------------------------------------------------------------
// merge_split: combine the two halves of each split item (flash merge).
// One block per split item; memory-bound; runs after attn (kernel boundary
// provides ordering, no fences needed).
// ---------------------------------------------------------------------------
__global__ __launch_bounds__(256) void merge_split(const float* __restrict__ partb,
                                                   __hip_bfloat16* __restrict__ out) {
    const int sidx = blockIdx.x;           // 0..NSPLITI-1
    const int qt = 31 - (sidx >> 5);
    const int inner = sidx & 31;
    const int h = 15 - ((inner >> 1) & 15);
    const int b = inner & 1;
    const int q0 = qt * 64;
    const float* pA = partb + (size_t)(sidx * 2) * PSLOT;
    const float* pB = pA + PSLOT;
    const int t = threadIdx.x;
    const int row = t >> 2, c0 = (t & 3) * 16;

    const float mA = pA[4096 + row], lA = pA[4160 + row];
    const float mB = pB[4096 + row], lB = pB[4160 + row];
    const float mm = fmaxf(mA, mB);
    const float fA = __exp2(mA - mm), fB = __exp2(mB - mm);
    const float inv = 1.f / (lA * fA + lB * fB);
    const float wA = fA * inv, wB = fB * inv;

    __hip_bfloat16* dst = &out[((size_t)(b * S_ + q0 + row)) * 1024 + h * 64 + c0];
    alignas(16) __hip_bfloat16 tmp[16];
#pragma unroll
    for (int j = 0; j < 16; j += 4) {
        f32x4 a = *(const f32x4*)&pA[row * 64 + c0 + j];
        f32x4 v = *(const f32x4*)&pB[row * 64 + c0 + j];
#pragma unroll
        for (int e = 0; e < 4; ++e)
            tmp[j + e] = __float2bfloat16(a[e] * wA + v[e] * wB);
    }
    *(short8*)&dst[0] = *(short8*)&tmp[0];
    *(short8*)&dst[8] = *(short8*)&tmp[8];
}

// ---------------------------------------------------------------------------
extern "C" void kernel_launch(void* const* d_in, const int* in_sizes, int n_in,
                              void* d_out, int out_size, void* d_ws, size_t ws_size,
                              hipStream_t stream) {
    const float* inputs = (const float*)d_in[0];
    const float* amask  = (const float*)d_in[1];
    const float* Wq     = (const float*)d_in[2];
    const float* Wk     = (const float*)d_in[3];
    const float* Wv     = (const float*)d_in[4];
    const float* Wo     = (const float*)d_in[5];
    const float* events = (const float*)d_in[6];
    float* out = (float*)d_out;

    // ws: Ax 8MB | Wt 8MB | qkv 24MB | ao 8MB | lk | sims | topk | ctr
    // During attn, [0 .. 14.68MB) is dead (Ax + Wq/Wk/Wv-transposed; gemm1
    // done, gemm2 only needs Wo-transposed at +14.68MB). The 832 partial
    // slots (14.05MB) live there.
    __hip_bfloat16* Ax  = (__hip_bfloat16*)d_ws;
    __hip_bfloat16* Wt  = Ax + (size_t)NROW * 1024;
    __hip_bfloat16* qkv = Wt + (size_t)4096 * 1024;
    __hip_bfloat16* ao  = qkv + (size_t)NROW * 3072;
    float* lk   = (float*)(ao + (size_t)NROW * 1024);
    float* sims = lk + 2 * 1024;
    int* topk   = (int*)(sims + 2 * 1024);
    int* ctr    = topk + B_ * KTOT;
    float* partb = (float*)d_ws;    // aliases Ax + first 3/4 of Wt (dead)

    dim3 blk(256);
    prep<<<3104, blk, 0, stream>>>(inputs, Wq, Wk, Wv, Wo, Ax, Wt, lk, ctr);
    sims_kernel<<<dim3(250, B_), blk, 0, stream>>>(lk, events, sims);
    topk10_kernel<<<B_, 64, 0, stream>>>(sims, topk);
    gemm_mfma<__hip_bfloat16><<<dim3(24, 32), blk, 0, stream>>>(Ax, Wt, qkv, 3072);
    attn_mfma<<<1024, blk, 0, stream>>>(qkv, events, topk, amask, ao, ctr, partb);
    merge_split<<<NSPLITI, blk, 0, stream>>>(partb, ao);
    gemm_mfma64<float><<<dim3(8, 64), blk, 0, stream>>>(
        ao, Wt + (size_t)3072 * 1024, out, 1024);
}

// Round 6
// 241.656 us; speedup vs baseline: 1.5872x; 1.0578x over previous
//
#include <hip/hip_runtime.h>
#include <hip/hip_bf16.h>
#include <math.h>

// Problem constants
#define B_   2
#define S_   2048
#define DM_  1024
#define H_   16
#define HD_  64
#define MEM_ 1000
#define KTOT 10
#define NROW (B_ * S_)          // 4096
#define NEG9 (-1e9f)
#define LDK  72                 // bf16 row stride in attention LDS tiles
#define QITEMS 128              // items per XCD queue: 32 qt x 4 streams
#define SC_  0.18033688f        // 0.125 * log2(e)  (QK scale, log2 domain)
#define TH_  170.238f           // 118 * log2(e)    (exact-underflow cutoff)

typedef __attribute__((ext_vector_type(8))) short short8;
typedef __attribute__((ext_vector_type(4))) float f32x4;

__device__ __forceinline__ float __exp2(float x) { return __builtin_amdgcn_exp2f(x); }

// async global->LDS, 16B per lane, dest = wave-uniform base + lane*16
__device__ __forceinline__ void gll16(const __hip_bfloat16* g, __hip_bfloat16* l) {
    __builtin_amdgcn_global_load_lds(
        (const __attribute__((address_space(1))) void*)g,
        (__attribute__((address_space(3))) void*)l, 16, 0, 0);
}

// ---------------------------------------------------------------------------
// prep: fused prologue (independent parts, branch on block range).
//   blocks [0,2048):    inputs fp32 -> bf16 Ax
//   blocks [2048,3072): weights fp32 -> transposed bf16 Wt[g*1024+n][k]
//   blocks [3072,3104): last-row K in fp32 (retrieval stays exact)
//   block 0, tid<8:     zero the 8 per-XCD work-steal counters
// ---------------------------------------------------------------------------
__global__ __launch_bounds__(256) void prep(const float* __restrict__ inputs,
                                            const float* __restrict__ Wq,
                                            const float* __restrict__ Wk,
                                            const float* __restrict__ Wv,
                                            const float* __restrict__ Wo,
                                            __hip_bfloat16* __restrict__ Ax,
                                            __hip_bfloat16* __restrict__ Wt,
                                            float* __restrict__ lk,
                                            int* __restrict__ ctr) {
    const int bx = blockIdx.x, tid = threadIdx.x;
    if (bx == 0 && tid < 8) ctr[tid] = 0;

    if (bx < 2048) {
        const size_t i = ((size_t)bx * 256 + tid) * 8;
        float4 a = *(const float4*)&inputs[i];
        float4 b = *(const float4*)&inputs[i + 4];
        alignas(16) __hip_bfloat16 t[8];
        t[0] = __float2bfloat16(a.x); t[1] = __float2bfloat16(a.y);
        t[2] = __float2bfloat16(a.z); t[3] = __float2bfloat16(a.w);
        t[4] = __float2bfloat16(b.x); t[5] = __float2bfloat16(b.y);
        t[6] = __float2bfloat16(b.z); t[7] = __float2bfloat16(b.w);
        *(short8*)&Ax[i] = *(short8*)t;
        return;
    }
    if (bx < 3072) {
        const int idx = bx - 2048;
        const int g = idx >> 8, rem = idx & 255;
        const float* W = (g == 0) ? Wq : (g == 1) ? Wk : (g == 2) ? Wv : Wo;
        const int n0 = (rem & 15) * 64, k0 = (rem >> 4) * 64;
        __shared__ float T[64][65];
        {
            const int r = tid >> 4, c4 = (tid & 15) * 4;
#pragma unroll
            for (int p = 0; p < 4; ++p) {
                float4 v = *(const float4*)&W[(size_t)(k0 + r + p * 16) * 1024 + n0 + c4];
                T[r + p * 16][c4 + 0] = v.x; T[r + p * 16][c4 + 1] = v.y;
                T[r + p * 16][c4 + 2] = v.z; T[r + p * 16][c4 + 3] = v.w;
            }
        }
        __syncthreads();
        {
            const int n = tid >> 3, off = (tid & 7) * 8;
#pragma unroll
            for (int p = 0; p < 2; ++p) {
                const int nn = n + p * 32;
                alignas(16) __hip_bfloat16 t[8];
#pragma unroll
                for (int j = 0; j < 8; ++j) t[j] = __float2bfloat16(T[off + j][nn]);
                *(short8*)&Wt[((size_t)(g * 1024 + n0 + nn)) * 1024 + k0 + off] = *(short8*)t;
            }
        }
        return;
    }
    {   // lastk: lk[b,:] = inputs[b, S-1, :] @ Wk (fp32)
        const int idx = bx - 3072;
        const int xblk = idx & 15, b = idx >> 4;
        const int cl = tid & 63;
        const int col = xblk * 64 + cl;
        const int kq = tid >> 6;
        __shared__ float xr[1024];
        __shared__ float part[4][64];
        for (int i = tid; i < 1024; i += 256)
            xr[i] = inputs[((size_t)(b * S_ + S_ - 1)) * 1024 + i];
        __syncthreads();
        float acc = 0.f;
#pragma unroll 4
        for (int k = kq * 256; k < kq * 256 + 256; ++k)
            acc += xr[k] * Wk[(size_t)k * 1024 + col];
        part[kq][cl] = acc;
        __syncthreads();
        if (tid < 64)
            lk[b * 1024 + xblk * 64 + tid] =
                part[0][tid] + part[1][tid] + part[2][tid] + part[3][tid];
    }
}

// ---------------------------------------------------------------------------
// bf16 MFMA GEMM, m97 structure + T1 XCD-aware block swizzle (bijective:
// grid counts are multiples of 8). Neighboring blocks within an XCD chunk
// share A row-panels -> panel reuse hits the XCD-private L2.
// ---------------------------------------------------------------------------
__device__ __forceinline__ void store_out(__hip_bfloat16* p, float x) { *p = __float2bfloat16(x); }
__device__ __forceinline__ void store_out(float* p, float x) { *p = x; }

template <typename OutT>
__global__ __launch_bounds__(256) void gemm_mfma(const __hip_bfloat16* __restrict__ A,
                                                 const __hip_bfloat16* __restrict__ Bt,
                                                 OutT* __restrict__ C, int ldc) {
    __shared__ __hip_bfloat16 As[128 * 32];
    __shared__ __hip_bfloat16 Bs[128 * 32];
    const int tid = threadIdx.x;
    const int wave = tid >> 6, lane = tid & 63;
    const int quad = lane >> 4, lm = lane & 15;
    const int wr = wave >> 1, wc = wave & 1;
    const int bid = blockIdx.y * gridDim.x + blockIdx.x;
    const int cpx = (gridDim.x * gridDim.y) >> 3;
    const int xw = (bid & 7) * cpx + (bid >> 3);
    const int m0 = (xw / gridDim.x) * 128, n0 = (xw % gridDim.x) * 128;

    const int r0 = tid >> 2, c0 = (tid & 3) * 8;
    const __hip_bfloat16* ga0 = &A[(size_t)(m0 + r0) * 1024 + c0];
    const __hip_bfloat16* ga1 = &A[(size_t)(m0 + 64 + r0) * 1024 + c0];
    const __hip_bfloat16* gb0 = &Bt[(size_t)(n0 + r0) * 1024 + c0];
    const __hip_bfloat16* gb1 = &Bt[(size_t)(n0 + 64 + r0) * 1024 + c0];
    __hip_bfloat16* la0 = &As[(wave * 64) * 8];
    __hip_bfloat16* la1 = &As[(256 + wave * 64) * 8];
    __hip_bfloat16* lb0 = &Bs[(wave * 64) * 8];
    __hip_bfloat16* lb1 = &Bs[(256 + wave * 64) * 8];

    f32x4 acc[4][4];
#pragma unroll
    for (int i = 0; i < 4; ++i)
#pragma unroll
        for (int j = 0; j < 4; ++j) acc[i][j] = (f32x4){0.f, 0.f, 0.f, 0.f};

    for (int k0 = 0; k0 < 1024; k0 += 32) {
        __syncthreads();
        gll16(ga0 + k0, la0);
        gll16(ga1 + k0, la1);
        gll16(gb0 + k0, lb0);
        gll16(gb1 + k0, lb1);
        __syncthreads();
        short8 af[4], bf4[4];
#pragma unroll
        for (int mt = 0; mt < 4; ++mt)
            af[mt] = *(const short8*)&As[(wr * 64 + mt * 16 + lm) * 32 + quad * 8];
#pragma unroll
        for (int nt = 0; nt < 4; ++nt)
            bf4[nt] = *(const short8*)&Bs[(wc * 64 + nt * 16 + lm) * 32 + quad * 8];
#pragma unroll
        for (int mt = 0; mt < 4; ++mt)
#pragma unroll
            for (int nt = 0; nt < 4; ++nt)
                acc[mt][nt] = __builtin_amdgcn_mfma_f32_16x16x32_bf16(
                    af[mt], bf4[nt], acc[mt][nt], 0, 0, 0);
    }
#pragma unroll
    for (int mt = 0; mt < 4; ++mt)
#pragma unroll
        for (int nt = 0; nt < 4; ++nt) {
            const int col = n0 + wc * 64 + nt * 16 + lm;
#pragma unroll
            for (int i = 0; i < 4; ++i) {
                const int row = m0 + wr * 64 + mt * 16 + quad * 4 + i;
                store_out(&C[(size_t)row * ldc + col], acc[mt][nt][i]);
            }
        }
}

// ---------------------------------------------------------------------------
// 64x128-tile variant for the out-projection GEMM (R9 win) + T1 swizzle.
// ---------------------------------------------------------------------------
template <typename OutT>
__global__ __launch_bounds__(256) void gemm_mfma64(const __hip_bfloat16* __restrict__ A,
                                                   const __hip_bfloat16* __restrict__ Bt,
                                                   OutT* __restrict__ C, int ldc) {
    __shared__ __hip_bfloat16 As[64 * 32];
    __shared__ __hip_bfloat16 Bs[128 * 32];
    const int tid = threadIdx.x;
    const int wave = tid >> 6, lane = tid & 63;
    const int quad = lane >> 4, lm = lane & 15;
    const int wr = wave >> 1, wc = wave & 1;
    const int bid = blockIdx.y * gridDim.x + blockIdx.x;
    const int cpx = (gridDim.x * gridDim.y) >> 3;
    const int xw = (bid & 7) * cpx + (bid >> 3);
    const int m0 = (xw / gridDim.x) * 64, n0 = (xw % gridDim.x) * 128;

    const int r0 = tid >> 2, c0 = (tid & 3) * 8;
    const __hip_bfloat16* ga  = &A[(size_t)(m0 + r0) * 1024 + c0];
    const __hip_bfloat16* gb0 = &Bt[(size_t)(n0 + r0) * 1024 + c0];
    const __hip_bfloat16* gb1 = &Bt[(size_t)(n0 + 64 + r0) * 1024 + c0];
    __hip_bfloat16* la  = &As[(wave * 64) * 8];
    __hip_bfloat16* lb0 = &Bs[(wave * 64) * 8];
    __hip_bfloat16* lb1 = &Bs[(256 + wave * 64) * 8];

    f32x4 acc[2][4];
#pragma unroll
    for (int i = 0; i < 2; ++i)
#pragma unroll
        for (int j = 0; j < 4; ++j) acc[i][j] = (f32x4){0.f, 0.f, 0.f, 0.f};

    for (int k0 = 0; k0 < 1024; k0 += 32) {
        __syncthreads();
        gll16(ga + k0, la);
        gll16(gb0 + k0, lb0);
        gll16(gb1 + k0, lb1);
        __syncthreads();
        short8 af[2], bf4[4];
#pragma unroll
        for (int mt = 0; mt < 2; ++mt)
            af[mt] = *(const short8*)&As[(wr * 32 + mt * 16 + lm) * 32 + quad * 8];
#pragma unroll
        for (int nt = 0; nt < 4; ++nt)
            bf4[nt] = *(const short8*)&Bs[(wc * 64 + nt * 16 + lm) * 32 + quad * 8];
#pragma unroll
        for (int mt = 0; mt < 2; ++mt)
#pragma unroll
            for (int nt = 0; nt < 4; ++nt)
                acc[mt][nt] = __builtin_amdgcn_mfma_f32_16x16x32_bf16(
                    af[mt], bf4[nt], acc[mt][nt], 0, 0, 0);
    }
#pragma unroll
    for (int mt = 0; mt < 2; ++mt)
#pragma unroll
        for (int nt = 0; nt < 4; ++nt) {
            const int col = n0 + wc * 64 + nt * 16 + lm;
#pragma unroll
            for (int i = 0; i < 4; ++i) {
                const int row = m0 + wr * 32 + mt * 16 + quad * 4 + i;
                store_out(&C[(size_t)row * ldc + col], acc[mt][nt][i]);
            }
        }
}

// ---------------------------------------------------------------------------
// sims + topk (unchanged).
// ---------------------------------------------------------------------------
__global__ __launch_bounds__(256) void sims_kernel(const float* __restrict__ lk,
                                                   const float* __restrict__ events,
                                                   float* __restrict__ sims) {
    const int b = blockIdx.y;
    const int tid = threadIdx.x;
    const int wave = tid >> 6, lane = tid & 63;
    __shared__ float qv[1024];
    for (int i = tid; i < 1024; i += 256)
        qv[i] = lk[b * 1024 + i];
    __syncthreads();

    const int m = blockIdx.x * 4 + wave;
    if (m >= MEM_) return;
    const float* ev = &events[(size_t)m * 1024];
    float dot = 0.f, nrm = 0.f;
    for (int d = lane; d < 1024; d += 64) {
        float e = ev[d];
        dot += qv[d] * e;
        nrm += e * e;
    }
    for (int off = 32; off; off >>= 1) {
        dot += __shfl_down(dot, off);
        nrm += __shfl_down(nrm, off);
    }
    if (lane == 0) sims[b * 1024 + m] = dot / (sqrtf(nrm) + 1e-8f);
}

__global__ __launch_bounds__(64) void topk10_kernel(const float* __restrict__ sims,
                                                    int* __restrict__ topk) {
    const int b = blockIdx.x;
    const int lane = threadIdx.x;
    const int base = lane * 16;
    float v[16];
#pragma unroll
    for (int j = 0; j < 16; ++j) {
        const int m = base + j;
        v[j] = (m < MEM_) ? sims[b * 1024 + m] : -INFINITY;
    }
    for (int it = 0; it < KTOT; ++it) {
        float best = -INFINITY; int bi = 0x7fffffff;
#pragma unroll
        for (int j = 0; j < 16; ++j)
            if (v[j] > best) { best = v[j]; bi = base + j; }
        for (int off = 32; off; off >>= 1) {
            const float ob = __shfl_xor(best, off);
            const int   oi = __shfl_xor(bi, off);
            if (ob > best || (ob == best && oi < bi)) { best = ob; bi = oi; }
        }
        if (lane == 0) topk[b * KTOT + it] = bi;
#pragma unroll
        for (int j = 0; j < 16; ++j)
            if (base + j == bi) v[j] = -INFINITY;
    }
}

// ---------------------------------------------------------------------------
// Flash attention R13 = EXACT R8 tile engine (best measured, 70.2 us) +
// XCD-partitioned work queues.
// Post-mortem model (fits R8-R12): the stall is K/V L2-MISS LATENCY. All 32
// (b,h) K/V streams = 16 MB, but each XCD has a private 4 MB L2. A single
// global work queue makes every XCD touch nearly all streams concurrently
// -> stage loads are HBM-latency (~900 cyc), barely hidden by one tile of
// compute (~2.1 us/tile wall). Everything that ADDED L2 pressure (R10
// fence writebacks, R11 dual streams/block, R12 partial dumps) regressed
// in proportion to its FETCH_SIZE delta.
// Fix: 8 queues; queue g = blockIdx.x & 7 (round-robin dispatch heuristic,
// same property T1 swizzle exploits) owns 4 of 32 streams x 32 q-tiles =
// 128 LPT-ordered items -> per-XCD K/V working set 2 MB < 4 MB L2.
// Grid 1024 (4 blocks/CU; LDS 30.7 KB, VGPR ~92): 128 blocks/queue ->
// ~1 item/block, no second-item tail.
// Kept verbatim from R8: single-buffer LDS, 2 barriers/tile, reg prefetch,
// ones-column l-accumulator, frozen-max cutoff, Q-in-regs.
// Kept from R10-R12 (correctness-proven): log2-domain softmax, zero-once Vt.
// ---------------------------------------------------------------------------
__global__ __launch_bounds__(256) void attn_mfma(
        const __hip_bfloat16* __restrict__ qkv,
        const float* __restrict__ events,
        const int* __restrict__ topk,
        const float* __restrict__ amask,
        __hip_bfloat16* __restrict__ out,
        int* __restrict__ ctr) {
    const int tid = threadIdx.x;
    const int wave = tid >> 6, lane = tid & 63;
    const int quad = lane >> 4, lm = lane & 15;
    const int g = blockIdx.x & 7;      // XCD queue id (round-robin heuristic)

    const __hip_bfloat16* qf = qkv;
    const __hip_bfloat16* kf = qkv + 1024;
    const __hip_bfloat16* vf = qkv + 2048;

    __shared__ __hip_bfloat16 Ks[64 * LDK];
    __shared__ __hip_bfloat16 Vt[80 * LDK];   // [d][kcol]; rows 64..79 static (64=ones)
    __shared__ __hip_bfloat16 Ps[64 * LDK];
    __shared__ float colb[64];
    __shared__ float redb[4];
    __shared__ int sItem;

    const int va = tid & 31, vdc = tid >> 5;
    const int vtok0 = va * 2, vd0 = vdc * 8;

    // one-time init: finite Vt fill (stale x P==0 = 0 needs finite, not NaN)
    // and the static ones/zero rows.
    for (int i = tid * 8; i < 64 * LDK; i += 256 * 8)
        *(int4*)&Vt[i] = make_int4(0, 0, 0, 0);
    for (int i = tid; i < 16 * LDK; i += 256) {
        const int r = i / LDK;
        Vt[64 * LDK + i] = __float2bfloat16(r == 0 ? 1.0f : 0.0f);
    }

    for (;;) {
        __syncthreads();    // prev item's LDS readers done; also covers Vt init
        if (tid == 0) sItem = atomicAdd(&ctr[g], 1);
        __syncthreads();
        const int n = sItem;
        if (n >= QITEMS) break;

        // queue-local decode: qt descending (LPT), 4 streams per queue
        const int qt = 31 - (n >> 2);
        const int s  = g * 4 + (n & 3);          // stream id 0..31
        const int h  = 15 - (s >> 1);
        const int b  = s & 1;
        const int q0 = qt * 64;
        const float slope2 = __exp2(-0.5f * (float)(h + 1)) * 1.44269504f;  // log2 dom

        short8 pk[2], pv0, pv1;
        float pam = 1.f;
        auto prefetchKV = [&](int kt) {
            const __hip_bfloat16* ks = &kf[((size_t)(b * S_ + kt * 64)) * 3072 + h * 64];
#pragma unroll
            for (int u = 0; u < 2; ++u) {
                int c = tid * 2 + u, row = c >> 3, off = (c & 7) * 8;
                pk[u] = *(const short8*)&ks[(size_t)row * 3072 + off];
            }
            const __hip_bfloat16* v0 =
                &vf[((size_t)(b * S_ + kt * 64 + vtok0)) * 3072 + h * 64 + vd0];
            pv0 = *(const short8*)v0;
            pv1 = *(const short8*)(v0 + 3072);
            if (tid < 64) pam = amask[b * S_ + kt * 64 + tid];
        };
        auto stageKV = [&](int kt) {
#pragma unroll
            for (int u = 0; u < 2; ++u) {
                int c = tid * 2 + u, row = c >> 3, off = (c & 7) * 8;
                *(short8*)&Ks[row * LDK + off] = pk[u];
            }
#pragma unroll
            for (int j = 0; j < 8; ++j) {
                short2 pr; pr.x = pv0[j]; pr.y = pv1[j];
                *(short2*)&Vt[(vd0 + j) * LDK + vtok0] = pr;
            }
            if (tid < 64)
                colb[tid] = fmaf(-slope2, (float)(kt * 64 + tid), (1.f - pam) * NEG9);
        };

        prefetchKV(0);      // earliest possible issue; consumed by stageKV(0)

        // ---- Q fragments straight into registers ----
        short8 qa[2];
        {
            const __hip_bfloat16* qsrc =
                &qf[((size_t)(b * S_ + q0 + wave * 16 + lm)) * 3072 + h * 64 + quad * 8];
            qa[0] = *(const short8*)qsrc;
            qa[1] = *(const short8*)(qsrc + 32);
        }
        // memory tile (K rows 0..9; Vt cols 0..9; stale rest exactly masked:
        // Ks via cc>=KTOT -> NEG9, Vt via Ps == 0.0 exactly)
        if (tid < 80) {
            const int tok = tid >> 3, d0 = (tid & 7) * 8;
            const int ev = topk[b * KTOT + tok];
            const float* es = &events[(size_t)ev * 1024 + h * 64 + d0];
#pragma unroll
            for (int j = 0; j < 8; ++j) {
                __hip_bfloat16 x = __float2bfloat16(es[j]);
                Ks[tok * LDK + d0 + j] = x;
                Vt[(d0 + j) * LDK + tok] = x;
            }
        }

        float m_[4], mshift[4];
        f32x4 Oa[5];        // Oa[4] = softmax denominator column
#pragma unroll
        for (int i = 0; i < 4; ++i) {
            m_[i] = -INFINITY;
            mshift[i] = -slope2 * (float)(q0 + wave * 16 + quad * 4 + i);
        }
#pragma unroll
        for (int nt = 0; nt < 5; ++nt) Oa[nt] = (f32x4){0.f, 0.f, 0.f, 0.f};

        auto qk = [&](f32x4* sa) {
#pragma unroll
            for (int nt = 0; nt < 4; ++nt) sa[nt] = (f32x4){0.f, 0.f, 0.f, 0.f};
#pragma unroll
            for (int ks2 = 0; ks2 < 2; ++ks2) {
#pragma unroll
                for (int nt = 0; nt < 4; ++nt) {
                    short8 bk = *(const short8*)&Ks[(nt * 16 + lm) * LDK + ks2 * 32 + quad * 8];
                    sa[nt] = __builtin_amdgcn_mfma_f32_16x16x32_bf16(qa[ks2], bk, sa[nt], 0, 0, 0);
                }
            }
        };
        auto pv = [&]() {
#pragma unroll
            for (int ks2 = 0; ks2 < 2; ++ks2) {
                short8 ap = *(const short8*)&Ps[(wave * 16 + lm) * LDK + ks2 * 32 + quad * 8];
#pragma unroll
                for (int nt = 0; nt < 5; ++nt) {   // nt=4: ones column -> l
                    short8 bv = *(const short8*)&Vt[(nt * 16 + lm) * LDK + ks2 * 32 + quad * 8];
                    Oa[nt] = __builtin_amdgcn_mfma_f32_16x16x32_bf16(ap, bv, Oa[nt], 0, 0, 0);
                }
            }
        };

        auto softmax_online = [&](const f32x4* sa, int kt, bool diag) {
            float cb[4];
            if (kt >= 0) {
#pragma unroll
                for (int nt = 0; nt < 4; ++nt) cb[nt] = colb[nt * 16 + lm];
            }
#pragma unroll
            for (int i = 0; i < 4; ++i) {
                const int lr = wave * 16 + quad * 4 + i;
                const int rg = q0 + lr;
                float s2[4];
#pragma unroll
                for (int nt = 0; nt < 4; ++nt) {
                    const int cc = nt * 16 + lm;
                    if (kt < 0) {
                        s2[nt] = (cc < KTOT) ? fmaf(sa[nt][i], SC_, mshift[i]) : NEG9;
                    } else {
                        float v = fmaf(sa[nt][i], SC_, cb[nt]);
                        s2[nt] = (diag && kt * 64 + cc > rg) ? NEG9 : v;
                    }
                }
                float rmax = fmaxf(fmaxf(s2[0], s2[1]), fmaxf(s2[2], s2[3]));
#pragma unroll
                for (int off = 1; off < 16; off <<= 1)
                    rmax = fmaxf(rmax, __shfl_xor(rmax, off, 16));
                const float newm = fmaxf(m_[i], rmax);
                const float al = __exp2(m_[i] - newm);
                m_[i] = newm;
#pragma unroll
                for (int nt = 0; nt < 4; ++nt)
                    Ps[lr * LDK + nt * 16 + lm] = __float2bfloat16(__exp2(s2[nt] - newm));
#pragma unroll
                for (int nt = 0; nt < 5; ++nt)     // includes l-column
                    Oa[nt][i] *= al;
            }
        };

        auto softmax_fast = [&](const f32x4* sa, int cbase, bool diag) {
            float cb[4];
#pragma unroll
            for (int nt = 0; nt < 4; ++nt) cb[nt] = colb[nt * 16 + lm];
#pragma unroll
            for (int i = 0; i < 4; ++i) {
                const int lr = wave * 16 + quad * 4 + i;
                const float cm = m_[i];
                float p[4];
#pragma unroll
                for (int nt = 0; nt < 4; ++nt)
                    p[nt] = __exp2(fmaf(sa[nt][i], SC_, cb[nt]) - cm);
                if (diag) {
                    const int rg = q0 + lr;
#pragma unroll
                    for (int nt = 0; nt < 4; ++nt)
                        if (cbase + nt * 16 + lm > rg) p[nt] = 0.f;
                }
#pragma unroll
                for (int nt = 0; nt < 4; ++nt)
                    Ps[lr * LDK + nt * 16 + lm] = __float2bfloat16(p[nt]);
            }
        };

        // ---- memory tile (online) ----
        __syncthreads();            // publish mem tile
        {
            f32x4 sa[4];
            qk(sa);
            softmax_online(sa, -1, false);
            pv();
        }
        __syncthreads();            // mem readers done before stage overwrites
        // ---- kt = 0 (online) ----
        stageKV(0);
        if (qt >= 1) prefetchKV(1);
        __syncthreads();
        {
            f32x4 sa[4];
            qk(sa);
            softmax_online(sa, 0, qt == 0);
            pv();
        }

        // ---- freeze max; block-min(m) -> exact-underflow cutoff ----
        int ktend = 0;
        if (qt >= 1) {
            float mloc = fminf(fminf(m_[0], m_[1]), fminf(m_[2], m_[3]));
#pragma unroll
            for (int off = 1; off < 64; off <<= 1)
                mloc = fminf(mloc, __shfl_xor(mloc, off, 64));
            if (lane == 0) redb[wave] = mloc;
            __syncthreads();        // redb visible + first-tile readers done
            const float mmin = fminf(fminf(redb[0], redb[1]), fminf(redb[2], redb[3]));
            ktend = min(qt, (int)((TH_ - mmin) / (64.f * slope2)));
        }
        for (int kt = 1; kt <= ktend; ++kt) {
            __syncthreads();
            stageKV(kt);
            if (kt < ktend) prefetchKV(kt + 1);
            __syncthreads();
            f32x4 sa[4];
            qk(sa);
            softmax_fast(sa, kt * 64, kt == qt);
            pv();
        }

        // ---- epilogue: l lives in Oa[4] col 0 (lanes lm==0); broadcast ----
#pragma unroll
        for (int i = 0; i < 4; ++i) {
            const int lr = wave * 16 + quad * 4 + i;
            const float l = __shfl(Oa[4][i], (lane & 48));
            const float inv = 1.f / l;
            __hip_bfloat16* dst = &out[((size_t)(b * S_ + q0 + lr)) * 1024 + h * 64 + lm];
#pragma unroll
            for (int nt = 0; nt < 4; ++nt)
                dst[nt * 16] = __float2bfloat16(Oa[nt][i] * inv);
        }
    }
}

// ---------------------------------------------------------------------------
extern "C" void kernel_launch(void* const* d_in, const int* in_sizes, int n_in,
                              void* d_out, int out_size, void* d_ws, size_t ws_size,
                              hipStream_t stream) {
    const float* inputs = (const float*)d_in[0];
    const float* amask  = (const float*)d_in[1];
    const float* Wq     = (const float*)d_in[2];
    const float* Wk     = (const float*)d_in[3];
    const float* Wv     = (const float*)d_in[4];
    const float* Wo     = (const float*)d_in[5];
    const float* events = (const float*)d_in[6];
    float* out = (float*)d_out;

    // ws: Ax 8MB | Wt 8MB | qkv 24MB | ao 8MB | lk | sims | topk | ctr[8]
    __hip_bfloat16* Ax  = (__hip_bfloat16*)d_ws;
    __hip_bfloat16* Wt  = Ax + (size_t)NROW * 1024;
    __hip_bfloat16* qkv = Wt + (size_t)4096 * 1024;
    __hip_bfloat16* ao  = qkv + (size_t)NROW * 3072;
    float* lk   = (float*)(ao + (size_t)NROW * 1024);
    float* sims = lk + 2 * 1024;
    int* topk   = (int*)(sims + 2 * 1024);
    int* ctr    = topk + B_ * KTOT;

    dim3 blk(256);
    prep<<<3104, blk, 0, stream>>>(inputs, Wq, Wk, Wv, Wo, Ax, Wt, lk, ctr);
    sims_kernel<<<dim3(250, B_), blk, 0, stream>>>(lk, events, sims);
    topk10_kernel<<<B_, 64, 0, stream>>>(sims, topk);
    gemm_mfma<__hip_bfloat16><<<dim3(24, 32), blk, 0, stream>>>(Ax, Wt, qkv, 3072);
    attn_mfma<<<1024, blk, 0, stream>>>(qkv, events, topk, amask, ao, ctr);
    gemm_mfma64<float><<<dim3(8, 64), blk, 0, stream>>>(
        ao, Wt + (size_t)3072 * 1024, out, 1024);
}